// Round 8
// baseline (207.452 us; speedup 1.0000x reference)
//
#include <hip/hip_runtime.h>
#include <math.h>

// ---- problem constants ----
#define NB 2
#define NS 2048
#define NE 768
#define NF 3072
#define NHEAD 12
#define NTOK 4096   // B*S
#define LDW 1344    // padded inner dim for Aext/Wc (21*64)
#define VTS 2176    // Vt row stride (2048+128): 4352B = 17*256B -> rotates L2 channels

typedef __bf16 bf16;
typedef __bf16 bf16x2 __attribute__((ext_vector_type(2)));
typedef __bf16 bf16x4 __attribute__((ext_vector_type(4)));
typedef __bf16 bf16x8 __attribute__((ext_vector_type(8)));
typedef float  f32x4  __attribute__((ext_vector_type(4)));

__device__ __forceinline__ f32x4 mfma_bf16(bf16x8 a, bf16x8 b, f32x4 c) {
  return __builtin_amdgcn_mfma_f32_16x16x32_bf16(a, b, c, 0, 0, 0);
}

__device__ __forceinline__ float fast_exp2(float x) {
#if __has_builtin(__builtin_amdgcn_exp2f)
  return __builtin_amdgcn_exp2f(x);
#else
  return exp2f(x);
#endif
}

// async global->LDS, 16B per lane. LDS dest must be wave-uniform base + lane*16.
__device__ __forceinline__ void glds16(const void* g, void* l) {
  __builtin_amdgcn_global_load_lds((const __attribute__((address_space(1))) void*)g,
                                   (__attribute__((address_space(3))) void*)l,
                                   16, 0, 0);
}

// Counted-vmcnt pipeline barriers (tri-buf gemm64 structure).
__device__ __forceinline__ void pipe_barrier_keep4() {
  asm volatile("s_waitcnt vmcnt(4)" ::: "memory");
  __builtin_amdgcn_s_barrier();
  __builtin_amdgcn_sched_barrier(0);
}
__device__ __forceinline__ void pipe_barrier_drain() {
  asm volatile("s_waitcnt vmcnt(0)" ::: "memory");
  __builtin_amdgcn_s_barrier();
  __builtin_amdgcn_sched_barrier(0);
}

// XCD-band swizzle (gridDim.y % 8 == 0 at all call sites).
__device__ __forceinline__ void swz_xy(int& bx, int& by) {
  int gx = gridDim.x;
  int i = by*gx + bx;
  int xcd = i & 7, s = i >> 3;
  int bands = gridDim.y >> 3;
  by = xcd*bands + s / gx;
  bx = s % gx;
}

// ---------------- weight prep: fp32 -> bf16 (+ reshapes/concat) ----------------
__global__ void prep_kernel(const float* __restrict__ in_proj, const float* __restrict__ out_proj,
                            const float* __restrict__ ffn1_w, const float* __restrict__ ffn1_b,
                            const float* __restrict__ ffn2_w,
                            const float* __restrict__ hA_w1, const float* __restrict__ hA_b1,
                            const float* __restrict__ hA_w2, const float* __restrict__ hA_b2,
                            const float* __restrict__ hB_w1, const float* __restrict__ hB_b1,
                            const float* __restrict__ hB_w2,
                            const float* __restrict__ task,
                            bf16* __restrict__ Wqkv, bf16* __restrict__ Wo, bf16* __restrict__ W2,
                            bf16* __restrict__ W1ab, float* __restrict__ b1ab,
                            bf16* __restrict__ WBp, bf16* __restrict__ Wc,
                            bf16* __restrict__ task_bf)
{
  __shared__ float tb[64*130];
  int stride = gridDim.x * blockDim.x;
  int t0 = blockIdx.x * blockDim.x + threadIdx.x;
  // q rows (first 768) pre-scaled by (1/sqrt(HD)) * log2(e) so flash can use exp2
  const float QS = 0.125f * 1.44269504088896f;
  // vectorized fp32->bf16 casts (float4 in, bf16x4 out)
  for (int i = t0; i < (2304*768)/4; i += stride) {
    float4 v = ((const float4*)in_proj)[i];
    float sc = (i < (768*768)/4) ? QS : 1.0f;
    *(bf16x4*)(Wqkv + i*4) = (bf16x4){(bf16)(v.x*sc), (bf16)(v.y*sc), (bf16)(v.z*sc), (bf16)(v.w*sc)};
  }
  for (int i = t0; i < (768*768)/4; i += stride) {
    float4 v = ((const float4*)out_proj)[i];
    *(bf16x4*)(Wo + i*4) = (bf16x4){(bf16)v.x, (bf16)v.y, (bf16)v.z, (bf16)v.w};
  }
  for (int i = t0; i < (768*3072)/4; i += stride) {
    float4 v = ((const float4*)ffn2_w)[i];
    *(bf16x4*)(W2 + i*4) = (bf16x4){(bf16)v.x, (bf16)v.y, (bf16)v.z, (bf16)v.w};
  }
  for (int i = t0; i < (NTOK*128)/4; i += stride) {
    float4 v = ((const float4*)task)[i];
    *(bf16x4*)(task_bf + i*4) = (bf16x4){(bf16)v.x, (bf16)v.y, (bf16)v.z, (bf16)v.w};
  }
  for (int i = t0; i < 256*128;  i += stride)
    W1ab[i] = (bf16)(i < 128*128 ? hA_w1[i] : hB_w1[i - 128*128]);
  for (int i = t0; i < 256; i += stride) b1ab[i] = (i < 128) ? hA_b1[i] : hB_b1[i-128];

  // WBp[n=(r*128+h)][e] = hB_w2[r*768+e][h] via 64x128 LDS transpose
  for (int j0 = blockIdx.x*64; j0 < 3072; j0 += gridDim.x*64) {
    __syncthreads();
    for (int i = threadIdx.x; i < 64*128; i += 256) {
      int jr = i >> 7, hh = i & 127;
      tb[jr*130 + hh] = hB_w2[(long)(j0 + jr)*128 + hh];
    }
    __syncthreads();
    int r = j0 / 768, e0 = j0 % 768;
    for (int i = threadIdx.x; i < 128*64; i += 256) {
      int hh = i >> 6, jr = i & 63;
      WBp[(long)(r*128 + hh)*768 + e0 + jr] = (bf16)tb[jr*130 + hh];
    }
  }

  // Wc[f][0:768]=ffn1_w ; [768+h*4+r]=hA_w2[(f*4+r)][h] ; [1280+r]=hA_b2[f*4+r] ;
  // [1284]=ffn1_b[f] ; [1285:1344]=0.  (stride LDW=1344)
  for (int f = blockIdx.x; f < 3072; f += gridDim.x) {
    const float* hrow = hA_w2 + (long)f*512;
    bf16* wrow = Wc + (long)f*LDW;
    for (int c = threadIdx.x; c < 768; c += 256) wrow[c] = (bf16)ffn1_w[(long)f*768 + c];
    for (int i = threadIdx.x; i < 512; i += 256) {
      int r = i >> 7, h = i & 127;
      wrow[768 + h*4 + r] = (bf16)hrow[i];
    }
    if (threadIdx.x < 4)        wrow[1280 + threadIdx.x] = (bf16)hA_b2[f*4 + threadIdx.x];
    else if (threadIdx.x == 4)  wrow[1284] = (bf16)ffn1_b[f];
    else if (threadIdx.x < 64)  wrow[1280 + threadIdx.x] = (bf16)0.f;
  }
}

// ---------------- RMSNorm (fp32 in -> bf16 out, arbitrary out row stride) ------
__global__ __launch_bounds__(256) void rmsnorm_k(const float* __restrict__ x,
                                                 const float* __restrict__ w,
                                                 bf16* __restrict__ out, int ld_out)
{
  __shared__ float red[4];
  long t = blockIdx.x;
  const float* xr = x + t*NE;
  float ss = 0.f;
  #pragma unroll
  for (int i = 0; i < 3; i++) { float v = xr[threadIdx.x + i*256]; ss += v*v; }
  #pragma unroll
  for (int d = 1; d < 64; d <<= 1) ss += __shfl_xor(ss, d, 64);
  if ((threadIdx.x & 63) == 0) red[threadIdx.x >> 6] = ss;
  __syncthreads();
  float tot = red[0] + red[1] + red[2] + red[3];
  float scale = rsqrtf(tot * (1.f/768.f) + 1.1920928955078125e-07f);
  #pragma unroll
  for (int i = 0; i < 3; i++) {
    int idx = threadIdx.x + i*256;
    out[t*ld_out + idx] = (bf16)(xr[idx] * scale * w[idx]);
  }
}

// ------- 256x192 BK=64 8-wave 4-phase GEMM (counted-vmcnt, 3-unit ledger) ------
// K10 only (M=4096, N=3072, K=1344 incl. zero-pad cols 1285..1343 of Aext/Wc).
// R6: 256-tile schedule = 37% per-CU but 192-block grid wasted 64 CUs.
// R7: full-chip 512-block grid but small tile = 31% per-CU. This tile is both:
// grid (3072/192, 4096/256) = (16,16) = 256 blocks = EXACTLY 1/CU; LDS 112KB;
// intensity 109.7 FLOP/B; 4x fewer barriers/FLOP than R7.
// 512 thr = 8 waves (2M x 4N); wave tile 128x48; acc 8x3 f32x4 (96 VGPR);
// 12 MFMA/phase. Superrow-swizzled LDS (proven 0-conflict stage+read).
//
// Stage units per tile (per thread): A-khalf = 2 glds16 (1024 chunks/512thr),
// B-FULL-BK = 3 glds16 (1536 chunks/512thr; khalf would be 1.5/thread ->
// non-uniform -> ledger breaks, so B is one unit). 7 loads/tile. Order:
// A0(Ph1), B(Ph2), A1(Ph3), none(Ph4), into buf cur^1 for tile t+1.
// Sync ledger (vmcnt per-wave; barrier makes it collective):
//  * Ph2-end vmcnt(5): outstanding = A1(t)(2)+A0'(2)+B'(3) = 7 -> drains
//    A1(t) for Ph3/Ph4 reads.  Tail: vmcnt(0).
//  * Ph4-end vmcnt(2): outstanding = A0'(2)+B'(3)+A1'(2) = 7 -> drains
//    A0',B' for Ph1/Ph2(t+1), leaves A1' in flight (steady state inv.).
//  * Prologue: stage A0,B,A1 of tile 0; vmcnt(2) drains A0,B.
//  * WAR: stages target buf cur^1; its readers' MFMAs complete before the
//    preceding phase barrier (compiler lgkmcnt before MFMA use).
__global__ __launch_bounds__(512, 2) void gemm_ph256(const bf16* __restrict__ A,
                                                     const bf16* __restrict__ Bm,
                                                     bf16* __restrict__ C,
                                                     int nt, int lda, int ldb, int ldc)
{
  __shared__ bf16 As[2][2][256*32];   // [buf][khalf]  64KB
  __shared__ bf16 Bs[2][2][192*32];   //               48KB -> 112KB total
  const int tid = threadIdx.x;
  int bx = blockIdx.x, by = blockIdx.y;
  swz_xy(bx, by);                     // gridDim=(16,16), y%8==0
  const int m0 = by * 256, n0 = bx * 192;
  const int w = tid >> 6, lane = tid & 63;
  const int quad = lane >> 4, l16 = lane & 15;
  const int wm = w >> 2, wn = w & 3;

  f32x4 acc[8][3];
  #pragma unroll
  for (int i = 0; i < 8; i++)
    #pragma unroll
    for (int j = 0; j < 3; j++) acc[i][j] = (f32x4){0.f,0.f,0.f,0.f};

  // A staging: 1024 chunks (256 rows x 32 cols / 8), chunks c = tid, tid+512.
  // superrow decode: R=c>>3, cc=(c&7)^(R&7), row=2R+(cc>>2), col8=(cc&3)*8.
  const int cA0 = tid, cA1 = tid + 512;
  const int RA0 = cA0 >> 3, xA0 = (cA0 & 7) ^ (RA0 & 7);
  const int RA1 = cA1 >> 3, xA1 = (cA1 & 7) ^ (RA1 & 7);
  const bf16* paA0 = A + (long)(m0 + 2*RA0 + (xA0 >> 2))*lda + (xA0 & 3)*8;
  const bf16* paA1 = A + (long)(m0 + 2*RA1 + (xA1 >> 2))*lda + (xA1 & 3)*8;

  // B staging: one full-BK unit = 1536 chunks, c = tid, tid+512, tid+1024;
  // kh = c/768, cc = c%768, then superrow decode within the khalf.
  const bf16* pbB[3];
  int bofs[3];
  #pragma unroll
  for (int i = 0; i < 3; ++i) {
    int c = tid + i*512;
    int kh = c / 768, cc = c - kh*768;
    int R = cc >> 3, cx = (cc & 7) ^ (R & 7);
    int row = 2*R + (cx >> 2), col8 = (cx & 3)*8;
    pbB[i] = Bm + (long)(n0 + row)*ldb + kh*32 + col8;
    bofs[i] = kh*(192*32) + cc*8;
  }

  auto stageA = [&](int buf, int kh, int kt) {
    glds16(paA0 + kt + kh*32, (void*)(&As[buf][kh][cA0*8]));
    glds16(paA1 + kt + kh*32, (void*)(&As[buf][kh][cA1*8]));
  };
  auto stageB = [&](int buf, int kt) {
    bf16* base = &Bs[buf][0][0];
    #pragma unroll
    for (int i = 0; i < 3; ++i)
      glds16(pbB[i] + kt, (void*)(base + bofs[i]));
  };

  const int Rh = l16 >> 1;
  const int jfr = (((l16 & 1) << 2) | quad) ^ Rh;
  const int aBase = wm*64, bBase = wn*24;   // superrow bases (128 / 48 rows)

  auto barrier = [] { __builtin_amdgcn_s_barrier(); __builtin_amdgcn_sched_barrier(0); };

  // prologue: tile 0 (A0,B,A1 = 7 loads); drain A0,B (oldest 5), keep A1
  stageA(0, 0, 0); stageB(0, 0); stageA(0, 1, 0);
  asm volatile("s_waitcnt vmcnt(2)" ::: "memory");
  barrier();

  for (int t = 0; t < nt; ++t) {
    const int cur = t & 1, nb = cur ^ 1;
    const bool more = (t + 1 < nt);
    const int kt1 = (t + 1) << 6;
    bf16x8 af[4], bfr[3];

    // ---- Ph1: kh=0, mh=0 (mi 0..3) ----
    #pragma unroll
    for (int j = 0; j < 4; ++j)
      af[j] = *(const bf16x8*)(&As[cur][0][(aBase + j*8 + Rh)*64 + jfr*8]);
    #pragma unroll
    for (int ni = 0; ni < 3; ++ni)
      bfr[ni] = *(const bf16x8*)(&Bs[cur][0][(bBase + ni*8 + Rh)*64 + jfr*8]);
    if (more) stageA(nb, 0, kt1);
    barrier();
    __builtin_amdgcn_s_setprio(1);
    #pragma unroll
    for (int j = 0; j < 4; ++j)
      #pragma unroll
      for (int ni = 0; ni < 3; ++ni)
        acc[j][ni] = mfma_bf16(af[j], bfr[ni], acc[j][ni]);
    __builtin_amdgcn_s_setprio(0);
    barrier();

    // ---- Ph2: kh=0, mh=1 (mi 4..7) ----
    #pragma unroll
    for (int j = 0; j < 4; ++j)
      af[j] = *(const bf16x8*)(&As[cur][0][(aBase + 32 + j*8 + Rh)*64 + jfr*8]);
    if (more) stageB(nb, kt1);
    barrier();
    __builtin_amdgcn_s_setprio(1);
    #pragma unroll
    for (int j = 0; j < 4; ++j)
      #pragma unroll
      for (int ni = 0; ni < 3; ++ni)
        acc[4 + j][ni] = mfma_bf16(af[j], bfr[ni], acc[4 + j][ni]);
    __builtin_amdgcn_s_setprio(0);
    if (more) asm volatile("s_waitcnt vmcnt(5)" ::: "memory");
    else      asm volatile("s_waitcnt vmcnt(0)" ::: "memory");
    barrier();   // A1(t) now visible to all waves

    // ---- Ph3: kh=1, mh=0 ----
    #pragma unroll
    for (int j = 0; j < 4; ++j)
      af[j] = *(const bf16x8*)(&As[cur][1][(aBase + j*8 + Rh)*64 + jfr*8]);
    #pragma unroll
    for (int ni = 0; ni < 3; ++ni)
      bfr[ni] = *(const bf16x8*)(&Bs[cur][1][(bBase + ni*8 + Rh)*64 + jfr*8]);
    if (more) stageA(nb, 1, kt1);
    barrier();
    __builtin_amdgcn_s_setprio(1);
    #pragma unroll
    for (int j = 0; j < 4; ++j)
      #pragma unroll
      for (int ni = 0; ni < 3; ++ni)
        acc[j][ni] = mfma_bf16(af[j], bfr[ni], acc[j][ni]);
    __builtin_amdgcn_s_setprio(0);
    barrier();

    // ---- Ph4: kh=1, mh=1 (no stage) ----
    #pragma unroll
    for (int j = 0; j < 4; ++j)
      af[j] = *(const bf16x8*)(&As[cur][1][(aBase + 32 + j*8 + Rh)*64 + jfr*8]);
    barrier();
    __builtin_amdgcn_s_setprio(1);
    #pragma unroll
    for (int j = 0; j < 4; ++j)
      #pragma unroll
      for (int ni = 0; ni < 3; ++ni)
        acc[4 + j][ni] = mfma_bf16(af[j], bfr[ni], acc[4 + j][ni]);
    __builtin_amdgcn_s_setprio(0);
    if (more) asm volatile("s_waitcnt vmcnt(2)" ::: "memory");
    barrier();   // A0,B of tile t+1 now visible to all waves
  }

  // epilogue: relu, bf16 out
  #pragma unroll
  for (int mi = 0; mi < 8; ++mi)
    #pragma unroll
    for (int ni = 0; ni < 3; ++ni) {
      int col = n0 + wn*48 + ni*16 + l16;
      #pragma unroll
      for (int r = 0; r < 4; ++r) {
        long row = m0 + wm*128 + mi*16 + quad*4 + r;
        float v = acc[mi][ni][r];
        C[row*ldc + col] = (bf16)(v > 0.f ? v : 0.f);
      }
    }
}

// ---------------- 64x64-tile GEMM, BK=64, XOR-swizzled LDS --------------------
// tri-buf counted-vmcnt pipeline.
template<typename OutT, bool RELU, bool BIAS, bool RES>
__global__ __launch_bounds__(256) void gemm64(const bf16* __restrict__ A,
                                              const bf16* __restrict__ Bm,
                                              OutT* __restrict__ C,
                                              const float* __restrict__ bias,
                                              const float* __restrict__ res,
                                              int K, int lda, int ldb, int ldc)
{
  __shared__ bf16 As[3][64*64];
  __shared__ bf16 Bs[3][64*64];
  const int tid = threadIdx.x;
  int bx = blockIdx.x, by = blockIdx.y;
  swz_xy(bx, by);
  const int m0 = by * 64, n0 = bx * 64;
  const int w = tid >> 6, lane = tid & 63;
  const int quad = lane >> 4, l16 = lane & 15;
  const int wy = w >> 1, wx = w & 1;
  const int sw = l16 & 7;

  f32x4 acc[2][2];
  #pragma unroll
  for (int i = 0; i < 2; i++)
    #pragma unroll
    for (int j = 0; j < 2; j++) acc[i][j] = (f32x4){0.f,0.f,0.f,0.f};

  const int c0 = tid, c1 = tid + 256;
  const int r0 = c0 >> 3, g0 = ((c0 & 7) ^ (r0 & 7)) * 8;
  const int r1 = c1 >> 3, g1 = ((c1 & 7) ^ (r1 & 7)) * 8;
  const bf16* pA0 = A  + (long)(m0 + r0)*lda + g0;
  const bf16* pA1 = A  + (long)(m0 + r1)*lda + g1;
  const bf16* pB0 = Bm + (long)(n0 + r0)*ldb + g0;
  const bf16* pB1 = Bm + (long)(n0 + r1)*ldb + g1;
  auto stage = [&](int buf) {
    glds16(pA0, (void*)(&As[buf][c0*8]));
    glds16(pA1, (void*)(&As[buf][c1*8]));
    glds16(pB0, (void*)(&Bs[buf][c0*8]));
    glds16(pB1, (void*)(&Bs[buf][c1*8]));
    pA0 += 64; pA1 += 64; pB0 += 64; pB1 += 64;
  };

  const int nsteps = K >> 6;
  stage(0);
  if (nsteps > 1) stage(1);
  pipe_barrier_keep4();

  int cur = 0, nx2 = 2;
  for (int s = 0; s < nsteps; ++s) {
    const bool more = (s + 2 < nsteps);
    if (more) stage(nx2);

    bf16x8 af[2][2], bfr[2][2];
    #pragma unroll
    for (int mi = 0; mi < 2; ++mi)
      #pragma unroll
      for (int kb = 0; kb < 2; ++kb)
        af[mi][kb] = *(const bf16x8*)(&As[cur][(wy*32 + mi*16 + l16)*64 + (((kb*4 + quad) ^ sw))*8]);
    #pragma unroll
    for (int ni = 0; ni < 2; ++ni)
      #pragma unroll
      for (int kb = 0; kb < 2; ++kb)
        bfr[ni][kb] = *(const bf16x8*)(&Bs[cur][(wx*32 + ni*16 + l16)*64 + (((kb*4 + quad) ^ sw))*8]);
    #pragma unroll
    for (int kb = 0; kb < 2; ++kb)
      #pragma unroll
      for (int mi = 0; mi < 2; ++mi)
        #pragma unroll
        for (int ni = 0; ni < 2; ++ni)
          acc[mi][ni] = mfma_bf16(af[mi][kb], bfr[ni][kb], acc[mi][ni]);

    if (more) pipe_barrier_keep4();
    else      pipe_barrier_drain();
    cur = (cur == 2) ? 0 : cur + 1;
    nx2 = (nx2 == 2) ? 0 : nx2 + 1;
  }

  #pragma unroll
  for (int mi = 0; mi < 2; ++mi)
    #pragma unroll
    for (int ni = 0; ni < 2; ++ni) {
      int col = n0 + wx*32 + ni*16 + l16;
      #pragma unroll
      for (int r = 0; r < 4; ++r) {
        long row = m0 + wy*32 + mi*16 + quad*4 + r;
        float v = acc[mi][ni][r];
        if (BIAS) v += bias[col];
        if (RES)  v += res[row*ldc + col];
        if (RELU) v = v > 0.f ? v : 0.f;
        C[row*ldc + col] = (OutT)v;
      }
    }
}

// ---- QKV GEMM: 64x64-tile variant with split epilogue (deep 2304-block grid):
// cols<1536 -> Qkv[t][2304]; V block -> Vt[bh][d][s] (row stride VTS) directly.
__global__ __launch_bounds__(256) void gemm_qkv64(const bf16* __restrict__ A,
                                                  const bf16* __restrict__ Bm,
                                                  bf16* __restrict__ Qkv,
                                                  bf16* __restrict__ Vt)
{
  __shared__ bf16 As[3][64*64];
  __shared__ bf16 Bs[3][64*64];
  const int tid = threadIdx.x;
  int bx = blockIdx.x, by = blockIdx.y;
  swz_xy(bx, by);
  const int m0 = by * 64, n0 = bx * 64;
  const int w = tid >> 6, lane = tid & 63;
  const int quad = lane >> 4, l16 = lane & 15;
  const int wy = w >> 1, wx = w & 1;
  const int sw = l16 & 7;

  f32x4 acc[2][2];
  #pragma unroll
  for (int i = 0; i < 2; i++)
    #pragma unroll
    for (int j = 0; j < 2; j++) acc[i][j] = (f32x4){0.f,0.f,0.f,0.f};

  const int c0 = tid, c1 = tid + 256;
  const int r0 = c0 >> 3, g0 = ((c0 & 7) ^ (r0 & 7)) * 8;
  const int r1 = c1 >> 3, g1 = ((c1 & 7) ^ (r1 & 7)) * 8;
  const bf16* pA0 = A  + (long)(m0 + r0)*768 + g0;
  const bf16* pA1 = A  + (long)(m0 + r1)*768 + g1;
  const bf16* pB0 = Bm + (long)(n0 + r0)*768 + g0;
  const bf16* pB1 = Bm + (long)(n0 + r1)*768 + g1;
  auto stage = [&](int buf) {
    glds16(pA0, (void*)(&As[buf][c0*8]));
    glds16(pA1, (void*)(&As[buf][c1*8]));
    glds16(pB0, (void*)(&Bs[buf][c0*8]));
    glds16(pB1, (void*)(&Bs[buf][c1*8]));
    pA0 += 64; pA1 += 64; pB0 += 64; pB1 += 64;
  };

  stage(0);
  stage(1);
  pipe_barrier_keep4();

  int cur = 0, nx2 = 2;
  for (int s = 0; s < 12; ++s) {           // K=768
    const bool more = (s + 2 < 12);
    if (more) stage(nx2);

    bf16x8 af[2][2], bfr[2][2];
    #pragma unroll
    for (int mi = 0; mi < 2; ++mi)
      #pragma unroll
      for (int kb = 0; kb < 2; ++kb)
        af[mi][kb] = *(const bf16x8*)(&As[cur][(wy*32 + mi*16 + l16)*64 + (((kb*4 + quad) ^ sw))*8]);
    #pragma unroll
    for (int ni = 0; ni < 2; ++ni)
      #pragma unroll
      for (int kb = 0; kb < 2; ++kb)
        bfr[ni][kb] = *(const bf16x8*)(&Bs[cur][(wx*32 + ni*16 + l16)*64 + (((kb*4 + quad) ^ sw))*8]);
    #pragma unroll
    for (int kb = 0; kb < 2; ++kb)
      #pragma unroll
      for (int mi = 0; mi < 2; ++mi)
        #pragma unroll
        for (int ni = 0; ni < 2; ++ni)
          acc[mi][ni] = mfma_bf16(af[mi][kb], bfr[ni][kb], acc[mi][ni]);

    if (more) pipe_barrier_keep4();
    else      pipe_barrier_drain();
    cur = (cur == 2) ? 0 : cur + 1;
    nx2 = (nx2 == 2) ? 0 : nx2 + 1;
  }

  const int bb = m0 >> 11;                  // batch (tile is 2048-aligned)
  #pragma unroll
  for (int mi = 0; mi < 2; ++mi)
    #pragma unroll
    for (int ni = 0; ni < 2; ++ni) {
      int col = n0 + wx*32 + ni*16 + l16;
      #pragma unroll
      for (int r = 0; r < 4; ++r) {
        long row = m0 + wy*32 + mi*16 + quad*4 + r;
        bf16 v = (bf16)acc[mi][ni][r];
        if (col < 1536) {
          Qkv[row*2304 + col] = v;
        } else {
          int vc = col - 1536;
          int hh = vc >> 6, d = vc & 63;
          long srow = row & (NS-1);
          Vt[((long)(bb*NHEAD + hh)*64 + d)*VTS + srow] = v;
        }
      }
    }
}

// ---------------- flash attention v7 (R2-best): 4 waves, KV-split, V in LDS ---
__global__ __launch_bounds__(256, 2) void flash_attn(const bf16* __restrict__ Qkv,
                                                     const bf16* __restrict__ Vt,
                                                     bf16* __restrict__ Ctx)
{
  __shared__ bf16 Ks[2][2][64*64];   // [pair][buf]
  __shared__ bf16 Vs[2][2][64*64];

  const int tid = threadIdx.x;
  const int w = tid >> 6, lane = tid & 63;
  const int quad = lane >> 4, l16 = lane & 15;
  const int pair = w >> 1, qw = w & 1;
  int bx = blockIdx.x, by = blockIdx.y;
  swz_xy(bx, by);                    // bh-band per XCD -> K/V L2-resident
  const int bh = by;
  const int b = bh / NHEAD, h = bh % NHEAD;
  const int q0 = bx * 64;

  bf16x8 qf[2][2];   // [q-group][kb]
  #pragma unroll
  for (int mi = 0; mi < 2; ++mi) {
    const long tq = (long)(b*NS + q0 + qw*32 + mi*16 + l16);
    qf[mi][0] = *(const bf16x8*)(Qkv + tq*2304 + h*64 + quad*8);
    qf[mi][1] = *(const bf16x8*)(Qkv + tq*2304 + h*64 + 32 + quad*8);
  }

  bf16x8 ones;
  #pragma unroll
  for (int j = 0; j < 8; ++j) ones[j] = (bf16)1.0f;

  f32x4 o[2][4];
  f32x4 o5[2];
  #pragma unroll
  for (int mi = 0; mi < 2; ++mi) {
    o5[mi] = (f32x4){0.f,0.f,0.f,0.f};
    #pragma unroll
    for (int i = 0; i < 4; i++) o[mi][i] = (f32x4){0.f,0.f,0.f,0.f};
  }

  // staging: per pair, 128 threads x 4 chunks each for K and V (512 = 64x64)
  const int ptid = tid & 127;
  const bf16* kp[4];
  const bf16* vp[4];
  int cc[4];
  #pragma unroll
  for (int i = 0; i < 4; ++i) {
    int c = ptid + i*128;
    cc[i] = c;
    int r = c >> 3, g = ((c & 7) ^ (r & 7)) * 8;
    kp[i] = Qkv + (long)(b*NS + pair*1024 + r)*2304 + 768 + h*64 + g;
    vp[i] = Vt + ((long)bh*64 + r)*VTS + pair*1024 + g;
  }
  auto stage = [&](int buf) {
    #pragma unroll
    for (int i = 0; i < 4; ++i) {
      glds16(kp[i], (void*)(&Ks[pair][buf][cc[i]*8]));
      glds16(vp[i], (void*)(&Vs[pair][buf][cc[i]*8]));
      kp[i] += (long)64*2304; vp[i] += 64;
    }
  };

  auto body = [&](int cur) {   // cur is a literal at every call site
    // K-fragments loaded once, reused by both q-groups
    bf16x8 kfr[4][2];
    #pragma unroll
    for (int nt = 0; nt < 4; ++nt)
      #pragma unroll
      for (int kb = 0; kb < 2; ++kb)
        kfr[nt][kb] = *(const bf16x8*)(&Ks[pair][cur][(nt*16 + l16)*64 + (((kb*4 + quad) ^ (l16 & 7)))*8]);

    bf16x8 pf[2][2];   // [q-group][ntp]
    #pragma unroll
    for (int mi = 0; mi < 2; ++mi) {
      f32x4 s[4];
      #pragma unroll
      for (int nt = 0; nt < 4; ++nt) {
        s[nt] = (f32x4){0.f,0.f,0.f,0.f};
        #pragma unroll
        for (int kb = 0; kb < 2; ++kb)
          s[nt] = mfma_bf16(kfr[nt][kb], qf[mi][kb], s[nt]);   // A=K, B=Q -> S^T
      }
      #pragma unroll
      for (int nt = 0; nt < 4; ++nt)
        #pragma unroll
        for (int r = 0; r < 4; ++r)
          pf[mi][nt >> 1][(nt & 1)*4 + r] = (bf16)fast_exp2(s[nt][r]);
    }
    // PV: V-fragments loaded once per ntp, reused by both q-groups
    #pragma unroll
    for (int ntp = 0; ntp < 2; ++ntp) {
      bf16x8 vf[4];
      #pragma unroll
      for (int dt = 0; dt < 4; ++dt) {
        int row = dt*16 + l16;                       // d
        int cA = ntp*4 + (quad >> 1);
        int base = row*64 + (quad & 1)*4;
        bf16x4 va = *(const bf16x4*)(&Vs[pair][cur][base + ((cA       ^ (row & 7)) << 3)]);
        bf16x4 vb = *(const bf16x4*)(&Vs[pair][cur][base + (((cA + 2) ^ (row & 7)) << 3)]);
        vf[dt] = (bf16x8){va[0],va[1],va[2],va[3], vb[0],vb[1],vb[2],vb[3]};
      }
      #pragma unroll
      for (int mi = 0; mi < 2; ++mi) {
        #pragma unroll
        for (int dt = 0; dt < 4; ++dt)
          o[mi][dt] = mfma_bf16(pf[mi][ntp], vf[dt], o[mi][dt]);
        o5[mi] = mfma_bf16(pf[mi][ntp], ones, o5[mi]);   // lsum in C-layout
      }
    }
  };

  stage(0);
  __builtin_amdgcn_s_waitcnt(0);
  __syncthreads();

  for (int t = 0; t < 16; t += 2) {   // 16 kv-tiles of 64 per pair
    stage(1);
    body(0);
    __builtin_amdgcn_s_waitcnt(0);
    __syncthreads();
    if (t + 2 < 16) stage(0);
    body(1);
    __builtin_amdgcn_s_waitcnt(0);
    __syncthreads();
  }

  // ---- combine: pair 1 -> LDS (f32 [64][68] + lsum[64], aliases Ks) ----
  float* Of = (float*)&Ks[0][0][0];
  float* Lf = Of + 64*68;
  const int rbase = qw*32;
  if (pair == 1) {
    #pragma unroll
    for (int mi = 0; mi < 2; ++mi)
      #pragma unroll
      for (int r = 0; r < 4; ++r) {
        int row = rbase + mi*16 + quad*4 + r;
        if (l16 == 0) Lf[row] = o5[mi][r];
        #pragma unroll
        for (int dt = 0; dt < 4; ++dt)
          Of[row*68 + dt*16 + l16] = o[mi][dt][r];
      }
  }
  __syncthreads();
  if (pair == 0) {
    #pragma unroll
    for (int mi = 0; mi < 2; ++mi)
      #pragma unroll
      for (int r = 0; r < 4; ++r) {
        int row = rbase + mi*16 + quad*4 + r;
        float inv = 1.f / (o5[mi][r] + Lf[row]);
        long trow = (long)(b*NS + q0 + row);
        #pragma unroll
        for (int dt = 0; dt < 4; ++dt)
          Ctx[trow*NE + h*64 + dt*16 + l16] =
            (bf16)((o[mi][dt][r] + Of[row*68 + dt*16 + l16]) * inv);
      }
  }
}

// ---------------- per-token: inter + build g/ones/zeros cols of Aext -----------
// 4 waves/block, one token per wave. Aext stride LDW; cols 1285..1343 zeroed.
// v2: xr read as bf16x2 (4B/lane coalescing), grow as bf16x8 store.
__global__ __launch_bounds__(256) void build_g(const bf16* __restrict__ HAB,
                                               const float* __restrict__ P,
                                               const float* __restrict__ hB_b2,
                                               bf16* __restrict__ Aext)
{
  long t = blockIdx.x*4 + (threadIdx.x >> 6);
  int lane = threadIdx.x & 63;
  const bf16* xr = Aext + t*LDW;             // cols 0..767 = xn2
  float acc[4] = {0.f, 0.f, 0.f, 0.f};
  #pragma unroll
  for (int k = 0; k < 6; ++k) {
    int idx = lane + k*64;                   // 0..383 (pairs)
    bf16x2 xv = *(const bf16x2*)(xr + idx*2);
    float x0 = (float)xv[0], x1 = (float)xv[1];
    #pragma unroll
    for (int r = 0; r < 4; ++r)
      acc[r] += x0 * hB_b2[r*768 + idx*2] + x1 * hB_b2[r*768 + idx*2 + 1];
  }
  const bf16* hB = HAB + t*256 + 128;
  const float* Pr = P + t*512;
  #pragma unroll
  for (int k = 0; k < 2; ++k) {
    int h = lane + k*64;
    float hv = (float)hB[h];
    #pragma unroll
    for (int r = 0; r < 4; ++r) acc[r] += hv * Pr[r*128 + h];
  }
  #pragma unroll
  for (int r = 0; r < 4; ++r)
    #pragma unroll
    for (int d = 1; d < 64; d <<= 1) acc[r] += __shfl_xor(acc[r], d, 64);

  bf16* grow = Aext + t*LDW + 768;
  const bf16* hA = HAB + t*256;
  bf16x8 gv;
  #pragma unroll
  for (int j = 0; j < 8; ++j) {
    int idx = lane*8 + j;                    // 0..511
    int h = idx >> 2, r = idx & 3;
    gv[j] = (bf16)((float)hA[h] * acc[r]);
  }
  *(bf16x8*)(grow + lane*8) = gv;
  if (lane < 4)       Aext[t*LDW + 1280 + lane] = (bf16)acc[lane];
  else if (lane == 4) Aext[t*LDW + 1284] = (bf16)1.0f;
  else                Aext[t*LDW + 1280 + lane] = (bf16)0.f;   // 1285..1343
}

// ---------------- host launcher ----------------
extern "C" void kernel_launch(void* const* d_in, const int* in_sizes, int n_in,
                              void* d_out, int out_size, void* d_ws, size_t ws_size,
                              hipStream_t stream)
{
  const float* src      = (const float*)d_in[0];
  const float* task     = (const float*)d_in[1];
  const float* norm1_w  = (const float*)d_in[2];
  const float* norm2_w  = (const float*)d_in[3];
  const float* in_proj  = (const float*)d_in[4];
  const float* out_proj = (const float*)d_in[5];
  const float* ffn1_w   = (const float*)d_in[6];
  const float* ffn1_b   = (const float*)d_in[7];
  const float* ffn2_w   = (const float*)d_in[8];
  const float* ffn2_b   = (const float*)d_in[9];
  const float* hA_w1    = (const float*)d_in[10];
  const float* hA_b1    = (const float*)d_in[11];
  const float* hA_w2    = (const float*)d_in[12];
  const float* hA_b2    = (const float*)d_in[13];
  const float* hB_w1    = (const float*)d_in[14];
  const float* hB_b1    = (const float*)d_in[15];
  const float* hB_w2    = (const float*)d_in[16];
  const float* hB_b2    = (const float*)d_in[17];
  float* out = (float*)d_out;

  char* ws = (char*)d_ws;
  size_t off = 0;
  auto alloc = [&](size_t bytes) { size_t o = off; off += (bytes + 255) & ~(size_t)255; return o; };
  bf16*  Wqkv   = (bf16*)(ws + alloc(2304*768*2));
  bf16*  Wo     = (bf16*)(ws + alloc(768*768*2));
  bf16*  W2     = (bf16*)(ws + alloc(768*3072*2));
  bf16*  W1ab   = (bf16*)(ws + alloc(256*128*2));
  float* b1ab   = (float*)(ws + alloc(256*4));
  bf16*  WBp    = (bf16*)(ws + alloc(512*768*2));
  bf16*  Wc     = (bf16*)(ws + alloc((size_t)3072*LDW*2));
  bf16*  taskbf = (bf16*)(ws + alloc((size_t)NTOK*128*2));
  bf16*  XC     = (bf16*)(ws + alloc((size_t)NTOK*768*2));    // Xn1, then Ctx
  char*  QKVH   = ws + alloc(25559040);                        // Qkv(18874368)+Vt(24*64*VTS*2=6684672) / Hbuf(25165824)
  bf16*  Qkv    = (bf16*)QKVH;
  bf16*  Vt     = (bf16*)(QKVH + 18874368);
  bf16*  Hbuf   = (bf16*)QKVH;
  float* Src2   = (float*)(ws + alloc((size_t)NTOK*768*4));
  bf16*  Aext   = (bf16*)(ws + alloc((size_t)NTOK*LDW*2));
  bf16*  HAB    = (bf16*)(ws + alloc((size_t)NTOK*256*2));
  float* P      = (float*)(ws + alloc((size_t)NTOK*512*4));

  // K0: weight prep / casts
  prep_kernel<<<dim3(1280), 256, 0, stream>>>(in_proj, out_proj, ffn1_w, ffn1_b, ffn2_w,
      hA_w1, hA_b1, hA_w2, hA_b2, hB_w1, hB_b1, hB_w2, task,
      Wqkv, Wo, W2, W1ab, b1ab, WBp, Wc, taskbf);
  // K1: x1 = rmsnorm(src, norm1_w) -> bf16
  rmsnorm_k<<<dim3(NTOK), 256, 0, stream>>>(src, norm1_w, XC, 768);
  // K2: qkv = x1 @ in_proj^T (64^2 deep grid); V -> Vt (stride VTS)
  gemm_qkv64<<<dim3(36,64), 256, 0, stream>>>(XC, Wqkv, Qkv, Vt);
  // K4: flash attention -> Ctx (reuses XC); 4 waves, KV-split, K+V in LDS
  flash_attn<<<dim3(32,24), 256, 0, stream>>>(Qkv, Vt, XC);
  // K5: src2 = src + ctx @ out_proj^T
  gemm64<float,false,false,true><<<dim3(12,64), 256, 0, stream>>>(XC, Wo, Src2, nullptr, src, 768, 768, 768, 768);
  // K6: xn2 = rmsnorm(src2, norm2_w) -> Aext cols 0..767 (stride LDW)
  rmsnorm_k<<<dim3(NTOK), 256, 0, stream>>>(Src2, norm2_w, Aext, LDW);
  // K7: HAB = relu(task @ W1ab^T + b1ab)
  gemm64<bf16,true,true,false><<<dim3(4,64), 256, 0, stream>>>(taskbf, W1ab, HAB, b1ab, nullptr, 128, 128, 128, 256);
  // K8: P = xn2 @ WBp^T
  gemm64<float,false,false,false><<<dim3(8,64), 256, 0, stream>>>(Aext, WBp, P, nullptr, nullptr, 768, LDW, 768, 512);
  // K9: inter + g -> Aext cols 768..1343
  build_g<<<dim3(NTOK/4), 256, 0, stream>>>(HAB, P, hB_b2, Aext);
  // K10: H = relu(Aext @ Wc^T) -- 256x192 4-phase counted-vmcnt, 256 blocks=1/CU
  gemm_ph256<<<dim3(16,16), 512, 0, stream>>>(Aext, Wc, Hbuf, 21, LDW, LDW, 3072);
  // K11: out = src2 + H @ ffn2_w^T + ffn2_b
  gemm64<float,false,true,true><<<dim3(12,64), 256, 0, stream>>>(Hbuf, W2, out, ffn2_b, Src2, 3072, 3072, 3072, 768);
}

// Round 10
// 205.294 us; speedup vs baseline: 1.0105x; 1.0105x over previous
//
#include <hip/hip_runtime.h>
#include <math.h>

// ---- problem constants ----
#define NB 2
#define NS 2048
#define NE 768
#define NF 3072
#define NHEAD 12
#define NTOK 4096   // B*S
#define LDW 1344    // padded inner dim for Aext/Wc (21*64)
#define VTS 2176    // Vt row stride (2048+128): 4352B = 17*256B -> rotates L2 channels

typedef __bf16 bf16;
typedef __bf16 bf16x2 __attribute__((ext_vector_type(2)));
typedef __bf16 bf16x4 __attribute__((ext_vector_type(4)));
typedef __bf16 bf16x8 __attribute__((ext_vector_type(8)));
typedef float  f32x4  __attribute__((ext_vector_type(4)));

__device__ __forceinline__ f32x4 mfma_bf16(bf16x8 a, bf16x8 b, f32x4 c) {
  return __builtin_amdgcn_mfma_f32_16x16x32_bf16(a, b, c, 0, 0, 0);
}

__device__ __forceinline__ float fast_exp2(float x) {
#if __has_builtin(__builtin_amdgcn_exp2f)
  return __builtin_amdgcn_exp2f(x);
#else
  return exp2f(x);
#endif
}

// async global->LDS, 16B per lane. LDS dest must be wave-uniform base + lane*16.
__device__ __forceinline__ void glds16(const void* g, void* l) {
  __builtin_amdgcn_global_load_lds((const __attribute__((address_space(1))) void*)g,
                                   (__attribute__((address_space(3))) void*)l,
                                   16, 0, 0);
}

// Counted-vmcnt pipeline barriers (tri-buf gemm64 structure).
__device__ __forceinline__ void pipe_barrier_keep4() {
  asm volatile("s_waitcnt vmcnt(4)" ::: "memory");
  __builtin_amdgcn_s_barrier();
  __builtin_amdgcn_sched_barrier(0);
}
__device__ __forceinline__ void pipe_barrier_drain() {
  asm volatile("s_waitcnt vmcnt(0)" ::: "memory");
  __builtin_amdgcn_s_barrier();
  __builtin_amdgcn_sched_barrier(0);
}

// XCD-band swizzle (gridDim.y % 8 == 0 at all call sites).
__device__ __forceinline__ void swz_xy(int& bx, int& by) {
  int gx = gridDim.x;
  int i = by*gx + bx;
  int xcd = i & 7, s = i >> 3;
  int bands = gridDim.y >> 3;
  by = xcd*bands + s / gx;
  bx = s % gx;
}

// ---------------- weight prep: fp32 -> bf16 (+ reshapes/concat) ----------------
__global__ void prep_kernel(const float* __restrict__ in_proj, const float* __restrict__ out_proj,
                            const float* __restrict__ ffn1_w, const float* __restrict__ ffn1_b,
                            const float* __restrict__ ffn2_w,
                            const float* __restrict__ hA_w1, const float* __restrict__ hA_b1,
                            const float* __restrict__ hA_w2, const float* __restrict__ hA_b2,
                            const float* __restrict__ hB_w1, const float* __restrict__ hB_b1,
                            const float* __restrict__ hB_w2,
                            const float* __restrict__ task,
                            bf16* __restrict__ Wqkv, bf16* __restrict__ Wo, bf16* __restrict__ W2,
                            bf16* __restrict__ W1ab, float* __restrict__ b1ab,
                            bf16* __restrict__ WBp, bf16* __restrict__ Wc,
                            bf16* __restrict__ task_bf)
{
  __shared__ float tb[64*130];
  int stride = gridDim.x * blockDim.x;
  int t0 = blockIdx.x * blockDim.x + threadIdx.x;
  // q rows (first 768) pre-scaled by (1/sqrt(HD)) * log2(e) so flash can use exp2
  const float QS = 0.125f * 1.44269504088896f;
  // vectorized fp32->bf16 casts (float4 in, bf16x4 out)
  for (int i = t0; i < (2304*768)/4; i += stride) {
    float4 v = ((const float4*)in_proj)[i];
    float sc = (i < (768*768)/4) ? QS : 1.0f;
    *(bf16x4*)(Wqkv + i*4) = (bf16x4){(bf16)(v.x*sc), (bf16)(v.y*sc), (bf16)(v.z*sc), (bf16)(v.w*sc)};
  }
  for (int i = t0; i < (768*768)/4; i += stride) {
    float4 v = ((const float4*)out_proj)[i];
    *(bf16x4*)(Wo + i*4) = (bf16x4){(bf16)v.x, (bf16)v.y, (bf16)v.z, (bf16)v.w};
  }
  for (int i = t0; i < (768*3072)/4; i += stride) {
    float4 v = ((const float4*)ffn2_w)[i];
    *(bf16x4*)(W2 + i*4) = (bf16x4){(bf16)v.x, (bf16)v.y, (bf16)v.z, (bf16)v.w};
  }
  for (int i = t0; i < (NTOK*128)/4; i += stride) {
    float4 v = ((const float4*)task)[i];
    *(bf16x4*)(task_bf + i*4) = (bf16x4){(bf16)v.x, (bf16)v.y, (bf16)v.z, (bf16)v.w};
  }
  for (int i = t0; i < 256*128;  i += stride)
    W1ab[i] = (bf16)(i < 128*128 ? hA_w1[i] : hB_w1[i - 128*128]);
  for (int i = t0; i < 256; i += stride) b1ab[i] = (i < 128) ? hA_b1[i] : hB_b1[i-128];

  // WBp[n=(r*128+h)][e] = hB_w2[r*768+e][h] via 64x128 LDS transpose
  for (int j0 = blockIdx.x*64; j0 < 3072; j0 += gridDim.x*64) {
    __syncthreads();
    for (int i = threadIdx.x; i < 64*128; i += 256) {
      int jr = i >> 7, hh = i & 127;
      tb[jr*130 + hh] = hB_w2[(long)(j0 + jr)*128 + hh];
    }
    __syncthreads();
    int r = j0 / 768, e0 = j0 % 768;
    for (int i = threadIdx.x; i < 128*64; i += 256) {
      int hh = i >> 6, jr = i & 63;
      WBp[(long)(r*128 + hh)*768 + e0 + jr] = (bf16)tb[jr*130 + hh];
    }
  }

  // Wc[f][0:768]=ffn1_w ; [768+h*4+r]=hA_w2[(f*4+r)][h] ; [1280+r]=hA_b2[f*4+r] ;
  // [1284]=ffn1_b[f] ; [1285:1344]=0.  (stride LDW=1344)
  for (int f = blockIdx.x; f < 3072; f += gridDim.x) {
    const float* hrow = hA_w2 + (long)f*512;
    bf16* wrow = Wc + (long)f*LDW;
    for (int c = threadIdx.x; c < 768; c += 256) wrow[c] = (bf16)ffn1_w[(long)f*768 + c];
    for (int i = threadIdx.x; i < 512; i += 256) {
      int r = i >> 7, h = i & 127;
      wrow[768 + h*4 + r] = (bf16)hrow[i];
    }
    if (threadIdx.x < 4)        wrow[1280 + threadIdx.x] = (bf16)hA_b2[f*4 + threadIdx.x];
    else if (threadIdx.x == 4)  wrow[1284] = (bf16)ffn1_b[f];
    else if (threadIdx.x < 64)  wrow[1280 + threadIdx.x] = (bf16)0.f;
  }
}

// ---------------- RMSNorm (fp32 in -> bf16 out, arbitrary out row stride) ------
__global__ __launch_bounds__(256) void rmsnorm_k(const float* __restrict__ x,
                                                 const float* __restrict__ w,
                                                 bf16* __restrict__ out, int ld_out)
{
  __shared__ float red[4];
  long t = blockIdx.x;
  const float* xr = x + t*NE;
  float ss = 0.f;
  #pragma unroll
  for (int i = 0; i < 3; i++) { float v = xr[threadIdx.x + i*256]; ss += v*v; }
  #pragma unroll
  for (int d = 1; d < 64; d <<= 1) ss += __shfl_xor(ss, d, 64);
  if ((threadIdx.x & 63) == 0) red[threadIdx.x >> 6] = ss;
  __syncthreads();
  float tot = red[0] + red[1] + red[2] + red[3];
  float scale = rsqrtf(tot * (1.f/768.f) + 1.1920928955078125e-07f);
  #pragma unroll
  for (int i = 0; i < 3; i++) {
    int idx = threadIdx.x + i*256;
    out[t*ld_out + idx] = (bf16)(xr[idx] * scale * w[idx]);
  }
}

// ------- 128x192 BK=64 4-wave 4-phase GEMM (counted-vmcnt schedule) ------------
// K10 (R7-verified best: 43.4us, MfmaUtil 30%). Grid (16,32) = 512 blocks =
// exactly 2/CU (R8 proved 2-block co-residency beats barrier amortization of
// bigger tiles at 1/CU); LDS 80KB = exactly 160/2.
// 256 thr = 4 waves (2M x 2N); wave tile 64x96; acc 4x6 f32x4; 12 MFMA/phase.
// Sync ledger: A-khalf=2, B-khalf=3 glds16/thread -> 10 loads/tile, order
// A0(Ph1),B0(Ph2),A1(Ph3),B1(Ph4) into buf cur^1.
//  * A0,B0(t): vmcnt(5) at Ph4(t-1) [10 outstanding -> oldest 5 drained].
//  * A1,B1(t): vmcnt(5) at Ph2(t). Tail: vmcnt(0) at Ph2, no Ph4 wait.
__global__ __launch_bounds__(256, 2) void gemm_ph(const bf16* __restrict__ A,
                                                  const bf16* __restrict__ Bm,
                                                  bf16* __restrict__ C,
                                                  int nt, int lda, int ldb, int ldc)
{
  __shared__ bf16 As[2][2][128*32];   // [buf][khalf]
  __shared__ bf16 Bs[2][2][192*32];   // 80KB total with As
  const int tid = threadIdx.x;
  int bx = blockIdx.x, by = blockIdx.y;
  swz_xy(bx, by);                     // gridDim=(16,32), y%8==0
  const int m0 = by * 128, n0 = bx * 192;
  const int w = tid >> 6, lane = tid & 63;
  const int quad = lane >> 4, l16 = lane & 15;
  const int wm = w >> 1, wn = w & 1;

  f32x4 acc[4][6];
  #pragma unroll
  for (int i = 0; i < 4; i++)
    #pragma unroll
    for (int j = 0; j < 6; j++) acc[i][j] = (f32x4){0.f,0.f,0.f,0.f};

  const int iA0 = tid,      RA0 = iA0 >> 3, cA0 = (iA0 & 7) ^ (RA0 & 7);
  const int iA1 = tid + 256,RA1 = iA1 >> 3, cA1 = (iA1 & 7) ^ (RA1 & 7);
  const int iB2 = tid + 512,RB2 = iB2 >> 3, cB2 = (iB2 & 7) ^ (RB2 & 7);
  const int rA0 = 2*RA0 + (cA0 >> 2), hA0c = (cA0 & 3)*8;
  const int rA1 = 2*RA1 + (cA1 >> 2), hA1c = (cA1 & 3)*8;
  const int rB2 = 2*RB2 + (cB2 >> 2), hB2c = (cB2 & 3)*8;
  const bf16* paA0 = A  + (long)(m0 + rA0)*lda + hA0c;
  const bf16* paA1 = A  + (long)(m0 + rA1)*lda + hA1c;
  const bf16* pbB0 = Bm + (long)(n0 + rA0)*ldb + hA0c;
  const bf16* pbB1 = Bm + (long)(n0 + rA1)*ldb + hA1c;
  const bf16* pbB2 = Bm + (long)(n0 + rB2)*ldb + hB2c;

  auto stageA = [&](int buf, int kh, int kt) {
    const int s = kt + kh*32;
    glds16(paA0 + s, (void*)(&As[buf][kh][tid*8]));
    glds16(paA1 + s, (void*)(&As[buf][kh][(tid + 256)*8]));
  };
  auto stageB = [&](int buf, int kh, int kt) {
    const int s = kt + kh*32;
    glds16(pbB0 + s, (void*)(&Bs[buf][kh][tid*8]));
    glds16(pbB1 + s, (void*)(&Bs[buf][kh][(tid + 256)*8]));
    glds16(pbB2 + s, (void*)(&Bs[buf][kh][(tid + 512)*8]));
  };

  const int Rh = l16 >> 1;
  const int jfr = (((l16 & 1) << 2) | quad) ^ Rh;
  const int aBase = wm*32, bBase = wn*48;   // superrow bases (64 / 96 rows)

  auto barrier = [] { __builtin_amdgcn_s_barrier(); __builtin_amdgcn_sched_barrier(0); };

  // prologue: tile 0 (A0,B0,A1,B1 = 10 loads); drain A0,B0, keep A1,B1 in flight
  stageA(0, 0, 0); stageB(0, 0, 0); stageA(0, 1, 0); stageB(0, 1, 0);
  asm volatile("s_waitcnt vmcnt(5)" ::: "memory");
  barrier();

  for (int t = 0; t < nt; ++t) {
    const int cur = t & 1, nb = cur ^ 1;
    const bool more = (t + 1 < nt);
    const int kt1 = (t + 1) << 6;
    bf16x8 af[2], bfr[6];

    // ---- Ph1: kb=0, mh=0 (mi 0..1) ----
    #pragma unroll
    for (int j = 0; j < 2; ++j)
      af[j] = *(const bf16x8*)(&As[cur][0][(aBase + j*8 + Rh)*64 + jfr*8]);
    #pragma unroll
    for (int ni = 0; ni < 6; ++ni)
      bfr[ni] = *(const bf16x8*)(&Bs[cur][0][(bBase + ni*8 + Rh)*64 + jfr*8]);
    if (more) stageA(nb, 0, kt1);
    barrier();
    __builtin_amdgcn_s_setprio(1);
    #pragma unroll
    for (int j = 0; j < 2; ++j)
      #pragma unroll
      for (int ni = 0; ni < 6; ++ni)
        acc[j][ni] = mfma_bf16(af[j], bfr[ni], acc[j][ni]);
    __builtin_amdgcn_s_setprio(0);
    barrier();

    // ---- Ph2: kb=0, mh=1 (mi 2..3) ----
    #pragma unroll
    for (int j = 0; j < 2; ++j)
      af[j] = *(const bf16x8*)(&As[cur][0][(aBase + 16 + j*8 + Rh)*64 + jfr*8]);
    if (more) stageB(nb, 0, kt1);
    barrier();
    __builtin_amdgcn_s_setprio(1);
    #pragma unroll
    for (int j = 0; j < 2; ++j)
      #pragma unroll
      for (int ni = 0; ni < 6; ++ni)
        acc[2 + j][ni] = mfma_bf16(af[j], bfr[ni], acc[2 + j][ni]);
    __builtin_amdgcn_s_setprio(0);
    if (more) asm volatile("s_waitcnt vmcnt(5)" ::: "memory");
    else      asm volatile("s_waitcnt vmcnt(0)" ::: "memory");
    barrier();   // A1,B1(t) now visible to all waves

    // ---- Ph3: kb=1, mh=0 ----
    #pragma unroll
    for (int j = 0; j < 2; ++j)
      af[j] = *(const bf16x8*)(&As[cur][1][(aBase + j*8 + Rh)*64 + jfr*8]);
    #pragma unroll
    for (int ni = 0; ni < 6; ++ni)
      bfr[ni] = *(const bf16x8*)(&Bs[cur][1][(bBase + ni*8 + Rh)*64 + jfr*8]);
    if (more) stageA(nb, 1, kt1);
    barrier();
    __builtin_amdgcn_s_setprio(1);
    #pragma unroll
    for (int j = 0; j < 2; ++j)
      #pragma unroll
      for (int ni = 0; ni < 6; ++ni)
        acc[j][ni] = mfma_bf16(af[j], bfr[ni], acc[j][ni]);
    __builtin_amdgcn_s_setprio(0);
    barrier();

    // ---- Ph4: kb=1, mh=1 ----
    #pragma unroll
    for (int j = 0; j < 2; ++j)
      af[j] = *(const bf16x8*)(&As[cur][1][(aBase + 16 + j*8 + Rh)*64 + jfr*8]);
    if (more) stageB(nb, 1, kt1);
    barrier();
    __builtin_amdgcn_s_setprio(1);
    #pragma unroll
    for (int j = 0; j < 2; ++j)
      #pragma unroll
      for (int ni = 0; ni < 6; ++ni)
        acc[2 + j][ni] = mfma_bf16(af[j], bfr[ni], acc[2 + j][ni]);
    __builtin_amdgcn_s_setprio(0);
    if (more) asm volatile("s_waitcnt vmcnt(5)" ::: "memory");
    barrier();   // A0,B0(t+1) now visible to all waves
  }

  // epilogue: relu, bf16 out
  #pragma unroll
  for (int mi = 0; mi < 4; ++mi)
    #pragma unroll
    for (int ni = 0; ni < 6; ++ni) {
      int col = n0 + wn*96 + ni*16 + l16;
      #pragma unroll
      for (int r = 0; r < 4; ++r) {
        long row = m0 + wm*64 + mi*16 + quad*4 + r;
        float v = acc[mi][ni][r];
        C[row*ldc + col] = (bf16)(v > 0.f ? v : 0.f);
      }
    }
}

// ---- QKV on the gemm_ph structure (exact clone; epilogue swapped) -------------
// M=4096, N=2304 (12 col-tiles of 192), K=768 (nt=12). Grid (12,32) = 384
// blocks = 1.5/CU; heavy CUs carry 2 blocks at the measured 4-phase 2-block
// rate (1488 FLOP/cyc/CU) -> ~21us bound. Epilogue: col<1536 -> Qkv[t][2304]
// (q pre-scaled in Wqkv rows); col>=1536 -> Vt[bh][d][s] scatter (stride VTS).
__global__ __launch_bounds__(256, 2) void gemm_ph_qkv(const bf16* __restrict__ A,
                                                      const bf16* __restrict__ Bm,
                                                      bf16* __restrict__ Qkv,
                                                      bf16* __restrict__ Vt)
{
  __shared__ bf16 As[2][2][128*32];
  __shared__ bf16 Bs[2][2][192*32];
  const int tid = threadIdx.x;
  int bx = blockIdx.x, by = blockIdx.y;
  swz_xy(bx, by);                     // gridDim=(12,32), y%8==0
  const int m0 = by * 128, n0 = bx * 192;
  const int w = tid >> 6, lane = tid & 63;
  const int quad = lane >> 4, l16 = lane & 15;
  const int wm = w >> 1, wn = w & 1;
  const int lda = 768, ldb = 768, nt = 12;

  f32x4 acc[4][6];
  #pragma unroll
  for (int i = 0; i < 4; i++)
    #pragma unroll
    for (int j = 0; j < 6; j++) acc[i][j] = (f32x4){0.f,0.f,0.f,0.f};

  const int iA0 = tid,      RA0 = iA0 >> 3, cA0 = (iA0 & 7) ^ (RA0 & 7);
  const int iA1 = tid + 256,RA1 = iA1 >> 3, cA1 = (iA1 & 7) ^ (RA1 & 7);
  const int iB2 = tid + 512,RB2 = iB2 >> 3, cB2 = (iB2 & 7) ^ (RB2 & 7);
  const int rA0 = 2*RA0 + (cA0 >> 2), hA0c = (cA0 & 3)*8;
  const int rA1 = 2*RA1 + (cA1 >> 2), hA1c = (cA1 & 3)*8;
  const int rB2 = 2*RB2 + (cB2 >> 2), hB2c = (cB2 & 3)*8;
  const bf16* paA0 = A  + (long)(m0 + rA0)*lda + hA0c;
  const bf16* paA1 = A  + (long)(m0 + rA1)*lda + hA1c;
  const bf16* pbB0 = Bm + (long)(n0 + rA0)*ldb + hA0c;
  const bf16* pbB1 = Bm + (long)(n0 + rA1)*ldb + hA1c;
  const bf16* pbB2 = Bm + (long)(n0 + rB2)*ldb + hB2c;

  auto stageA = [&](int buf, int kh, int kt) {
    const int s = kt + kh*32;
    glds16(paA0 + s, (void*)(&As[buf][kh][tid*8]));
    glds16(paA1 + s, (void*)(&As[buf][kh][(tid + 256)*8]));
  };
  auto stageB = [&](int buf, int kh, int kt) {
    const int s = kt + kh*32;
    glds16(pbB0 + s, (void*)(&Bs[buf][kh][tid*8]));
    glds16(pbB1 + s, (void*)(&Bs[buf][kh][(tid + 256)*8]));
    glds16(pbB2 + s, (void*)(&Bs[buf][kh][(tid + 512)*8]));
  };

  const int Rh = l16 >> 1;
  const int jfr = (((l16 & 1) << 2) | quad) ^ Rh;
  const int aBase = wm*32, bBase = wn*48;

  auto barrier = [] { __builtin_amdgcn_s_barrier(); __builtin_amdgcn_sched_barrier(0); };

  stageA(0, 0, 0); stageB(0, 0, 0); stageA(0, 1, 0); stageB(0, 1, 0);
  asm volatile("s_waitcnt vmcnt(5)" ::: "memory");
  barrier();

  for (int t = 0; t < nt; ++t) {
    const int cur = t & 1, nb = cur ^ 1;
    const bool more = (t + 1 < nt);
    const int kt1 = (t + 1) << 6;
    bf16x8 af[2], bfr[6];

    // ---- Ph1 ----
    #pragma unroll
    for (int j = 0; j < 2; ++j)
      af[j] = *(const bf16x8*)(&As[cur][0][(aBase + j*8 + Rh)*64 + jfr*8]);
    #pragma unroll
    for (int ni = 0; ni < 6; ++ni)
      bfr[ni] = *(const bf16x8*)(&Bs[cur][0][(bBase + ni*8 + Rh)*64 + jfr*8]);
    if (more) stageA(nb, 0, kt1);
    barrier();
    __builtin_amdgcn_s_setprio(1);
    #pragma unroll
    for (int j = 0; j < 2; ++j)
      #pragma unroll
      for (int ni = 0; ni < 6; ++ni)
        acc[j][ni] = mfma_bf16(af[j], bfr[ni], acc[j][ni]);
    __builtin_amdgcn_s_setprio(0);
    barrier();

    // ---- Ph2 ----
    #pragma unroll
    for (int j = 0; j < 2; ++j)
      af[j] = *(const bf16x8*)(&As[cur][0][(aBase + 16 + j*8 + Rh)*64 + jfr*8]);
    if (more) stageB(nb, 0, kt1);
    barrier();
    __builtin_amdgcn_s_setprio(1);
    #pragma unroll
    for (int j = 0; j < 2; ++j)
      #pragma unroll
      for (int ni = 0; ni < 6; ++ni)
        acc[2 + j][ni] = mfma_bf16(af[j], bfr[ni], acc[2 + j][ni]);
    __builtin_amdgcn_s_setprio(0);
    if (more) asm volatile("s_waitcnt vmcnt(5)" ::: "memory");
    else      asm volatile("s_waitcnt vmcnt(0)" ::: "memory");
    barrier();

    // ---- Ph3 ----
    #pragma unroll
    for (int j = 0; j < 2; ++j)
      af[j] = *(const bf16x8*)(&As[cur][1][(aBase + j*8 + Rh)*64 + jfr*8]);
    #pragma unroll
    for (int ni = 0; ni < 6; ++ni)
      bfr[ni] = *(const bf16x8*)(&Bs[cur][1][(bBase + ni*8 + Rh)*64 + jfr*8]);
    if (more) stageA(nb, 1, kt1);
    barrier();
    __builtin_amdgcn_s_setprio(1);
    #pragma unroll
    for (int j = 0; j < 2; ++j)
      #pragma unroll
      for (int ni = 0; ni < 6; ++ni)
        acc[j][ni] = mfma_bf16(af[j], bfr[ni], acc[j][ni]);
    __builtin_amdgcn_s_setprio(0);
    barrier();

    // ---- Ph4 ----
    #pragma unroll
    for (int j = 0; j < 2; ++j)
      af[j] = *(const bf16x8*)(&As[cur][1][(aBase + 16 + j*8 + Rh)*64 + jfr*8]);
    if (more) stageB(nb, 1, kt1);
    barrier();
    __builtin_amdgcn_s_setprio(1);
    #pragma unroll
    for (int j = 0; j < 2; ++j)
      #pragma unroll
      for (int ni = 0; ni < 6; ++ni)
        acc[2 + j][ni] = mfma_bf16(af[j], bfr[ni], acc[2 + j][ni]);
    __builtin_amdgcn_s_setprio(0);
    if (more) asm volatile("s_waitcnt vmcnt(5)" ::: "memory");
    barrier();
  }

  // epilogue: QKV split store (bf16, no relu)
  #pragma unroll
  for (int mi = 0; mi < 4; ++mi)
    #pragma unroll
    for (int ni = 0; ni < 6; ++ni) {
      int col = n0 + wn*96 + ni*16 + l16;
      #pragma unroll
      for (int r = 0; r < 4; ++r) {
        long row = m0 + wm*64 + mi*16 + quad*4 + r;
        bf16 v = (bf16)acc[mi][ni][r];
        if (col < 1536) {
          Qkv[row*2304 + col] = v;
        } else {
          int vc = col - 1536;
          int hh = vc >> 6, d = vc & 63;
          long bb = row >> 11;
          long srow = row & (NS-1);
          Vt[((bb*NHEAD + hh)*64 + d)*VTS + srow] = v;
        }
      }
    }
}

// ---------------- 64x64-tile GEMM, BK=64, XOR-swizzled LDS --------------------
// tri-buf counted-vmcnt pipeline.
template<typename OutT, bool RELU, bool BIAS, bool RES>
__global__ __launch_bounds__(256) void gemm64(const bf16* __restrict__ A,
                                              const bf16* __restrict__ Bm,
                                              OutT* __restrict__ C,
                                              const float* __restrict__ bias,
                                              const float* __restrict__ res,
                                              int K, int lda, int ldb, int ldc)
{
  __shared__ bf16 As[3][64*64];
  __shared__ bf16 Bs[3][64*64];
  const int tid = threadIdx.x;
  int bx = blockIdx.x, by = blockIdx.y;
  swz_xy(bx, by);
  const int m0 = by * 64, n0 = bx * 64;
  const int w = tid >> 6, lane = tid & 63;
  const int quad = lane >> 4, l16 = lane & 15;
  const int wy = w >> 1, wx = w & 1;
  const int sw = l16 & 7;

  f32x4 acc[2][2];
  #pragma unroll
  for (int i = 0; i < 2; i++)
    #pragma unroll
    for (int j = 0; j < 2; j++) acc[i][j] = (f32x4){0.f,0.f,0.f,0.f};

  const int c0 = tid, c1 = tid + 256;
  const int r0 = c0 >> 3, g0 = ((c0 & 7) ^ (r0 & 7)) * 8;
  const int r1 = c1 >> 3, g1 = ((c1 & 7) ^ (r1 & 7)) * 8;
  const bf16* pA0 = A  + (long)(m0 + r0)*lda + g0;
  const bf16* pA1 = A  + (long)(m0 + r1)*lda + g1;
  const bf16* pB0 = Bm + (long)(n0 + r0)*ldb + g0;
  const bf16* pB1 = Bm + (long)(n0 + r1)*ldb + g1;
  auto stage = [&](int buf) {
    glds16(pA0, (void*)(&As[buf][c0*8]));
    glds16(pA1, (void*)(&As[buf][c1*8]));
    glds16(pB0, (void*)(&Bs[buf][c0*8]));
    glds16(pB1, (void*)(&Bs[buf][c1*8]));
    pA0 += 64; pA1 += 64; pB0 += 64; pB1 += 64;
  };

  const int nsteps = K >> 6;
  stage(0);
  if (nsteps > 1) stage(1);
  pipe_barrier_keep4();

  int cur = 0, nx2 = 2;
  for (int s = 0; s < nsteps; ++s) {
    const bool more = (s + 2 < nsteps);
    if (more) stage(nx2);

    bf16x8 af[2][2], bfr[2][2];
    #pragma unroll
    for (int mi = 0; mi < 2; ++mi)
      #pragma unroll
      for (int kb = 0; kb < 2; ++kb)
        af[mi][kb] = *(const bf16x8*)(&As[cur][(wy*32 + mi*16 + l16)*64 + (((kb*4 + quad) ^ sw))*8]);
    #pragma unroll
    for (int ni = 0; ni < 2; ++ni)
      #pragma unroll
      for (int kb = 0; kb < 2; ++kb)
        bfr[ni][kb] = *(const bf16x8*)(&Bs[cur][(wx*32 + ni*16 + l16)*64 + (((kb*4 + quad) ^ sw))*8]);
    #pragma unroll
    for (int kb = 0; kb < 2; ++kb)
      #pragma unroll
      for (int mi = 0; mi < 2; ++mi)
        #pragma unroll
        for (int ni = 0; ni < 2; ++ni)
          acc[mi][ni] = mfma_bf16(af[mi][kb], bfr[ni][kb], acc[mi][ni]);

    if (more) pipe_barrier_keep4();
    else      pipe_barrier_drain();
    cur = (cur == 2) ? 0 : cur + 1;
    nx2 = (nx2 == 2) ? 0 : nx2 + 1;
  }

  #pragma unroll
  for (int mi = 0; mi < 2; ++mi)
    #pragma unroll
    for (int ni = 0; ni < 2; ++ni) {
      int col = n0 + wx*32 + ni*16 + l16;
      #pragma unroll
      for (int r = 0; r < 4; ++r) {
        long row = m0 + wy*32 + mi*16 + quad*4 + r;
        float v = acc[mi][ni][r];
        if (BIAS) v += bias[col];
        if (RES)  v += res[row*ldc + col];
        if (RELU) v = v > 0.f ? v : 0.f;
        C[row*ldc + col] = (OutT)v;
      }
    }
}

// ---------------- flash attention v7 (R2-best): 4 waves, KV-split, V in LDS ---
__global__ __launch_bounds__(256, 2) void flash_attn(const bf16* __restrict__ Qkv,
                                                     const bf16* __restrict__ Vt,
                                                     bf16* __restrict__ Ctx)
{
  __shared__ bf16 Ks[2][2][64*64];   // [pair][buf]
  __shared__ bf16 Vs[2][2][64*64];

  const int tid = threadIdx.x;
  const int w = tid >> 6, lane = tid & 63;
  const int quad = lane >> 4, l16 = lane & 15;
  const int pair = w >> 1, qw = w & 1;
  int bx = blockIdx.x, by = blockIdx.y;
  swz_xy(bx, by);                    // bh-band per XCD -> K/V L2-resident
  const int bh = by;
  const int b = bh / NHEAD, h = bh % NHEAD;
  const int q0 = bx * 64;

  bf16x8 qf[2][2];   // [q-group][kb]
  #pragma unroll
  for (int mi = 0; mi < 2; ++mi) {
    const long tq = (long)(b*NS + q0 + qw*32 + mi*16 + l16);
    qf[mi][0] = *(const bf16x8*)(Qkv + tq*2304 + h*64 + quad*8);
    qf[mi][1] = *(const bf16x8*)(Qkv + tq*2304 + h*64 + 32 + quad*8);
  }

  bf16x8 ones;
  #pragma unroll
  for (int j = 0; j < 8; ++j) ones[j] = (bf16)1.0f;

  f32x4 o[2][4];
  f32x4 o5[2];
  #pragma unroll
  for (int mi = 0; mi < 2; ++mi) {
    o5[mi] = (f32x4){0.f,0.f,0.f,0.f};
    #pragma unroll
    for (int i = 0; i < 4; i++) o[mi][i] = (f32x4){0.f,0.f,0.f,0.f};
  }

  // staging: per pair, 128 threads x 4 chunks each for K and V (512 = 64x64)
  const int ptid = tid & 127;
  const bf16* kp[4];
  const bf16* vp[4];
  int cc[4];
  #pragma unroll
  for (int i = 0; i < 4; ++i) {
    int c = ptid + i*128;
    cc[i] = c;
    int r = c >> 3, g = ((c & 7) ^ (r & 7)) * 8;
    kp[i] = Qkv + (long)(b*NS + pair*1024 + r)*2304 + 768 + h*64 + g;
    vp[i] = Vt + ((long)bh*64 + r)*VTS + pair*1024 + g;
  }
  auto stage = [&](int buf) {
    #pragma unroll
    for (int i = 0; i < 4; ++i) {
      glds16(kp[i], (void*)(&Ks[pair][buf][cc[i]*8]));
      glds16(vp[i], (void*)(&Vs[pair][buf][cc[i]*8]));
      kp[i] += (long)64*2304; vp[i] += 64;
    }
  };

  auto body = [&](int cur) {   // cur is a literal at every call site
    // K-fragments loaded once, reused by both q-groups
    bf16x8 kfr[4][2];
    #pragma unroll
    for (int nt = 0; nt < 4; ++nt)
      #pragma unroll
      for (int kb = 0; kb < 2; ++kb)
        kfr[nt][kb] = *(const bf16x8*)(&Ks[pair][cur][(nt*16 + l16)*64 + (((kb*4 + quad) ^ (l16 & 7)))*8]);

    bf16x8 pf[2][2];   // [q-group][ntp]
    #pragma unroll
    for (int mi = 0; mi < 2; ++mi) {
      f32x4 s[4];
      #pragma unroll
      for (int nt = 0; nt < 4; ++nt) {
        s[nt] = (f32x4){0.f,0.f,0.f,0.f};
        #pragma unroll
        for (int kb = 0; kb < 2; ++kb)
          s[nt] = mfma_bf16(kfr[nt][kb], qf[mi][kb], s[nt]);   // A=K, B=Q -> S^T
      }
      #pragma unroll
      for (int nt = 0; nt < 4; ++nt)
        #pragma unroll
        for (int r = 0; r < 4; ++r)
          pf[mi][nt >> 1][(nt & 1)*4 + r] = (bf16)fast_exp2(s[nt][r]);
    }
    // PV: V-fragments loaded once per ntp, reused by both q-groups
    #pragma unroll
    for (int ntp = 0; ntp < 2; ++ntp) {
      bf16x8 vf[4];
      #pragma unroll
      for (int dt = 0; dt < 4; ++dt) {
        int row = dt*16 + l16;                       // d
        int cA = ntp*4 + (quad >> 1);
        int base = row*64 + (quad & 1)*4;
        bf16x4 va = *(const bf16x4*)(&Vs[pair][cur][base + ((cA       ^ (row & 7)) << 3)]);
        bf16x4 vb = *(const bf16x4*)(&Vs[pair][cur][base + (((cA + 2) ^ (row & 7)) << 3)]);
        vf[dt] = (bf16x8){va[0],va[1],va[2],va[3], vb[0],vb[1],vb[2],vb[3]};
      }
      #pragma unroll
      for (int mi = 0; mi < 2; ++mi) {
        #pragma unroll
        for (int dt = 0; dt < 4; ++dt)
          o[mi][dt] = mfma_bf16(pf[mi][ntp], vf[dt], o[mi][dt]);
        o5[mi] = mfma_bf16(pf[mi][ntp], ones, o5[mi]);   // lsum in C-layout
      }
    }
  };

  stage(0);
  __builtin_amdgcn_s_waitcnt(0);
  __syncthreads();

  for (int t = 0; t < 16; t += 2) {   // 16 kv-tiles of 64 per pair
    stage(1);
    body(0);
    __builtin_amdgcn_s_waitcnt(0);
    __syncthreads();
    if (t + 2 < 16) stage(0);
    body(1);
    __builtin_amdgcn_s_waitcnt(0);
    __syncthreads();
  }

  // ---- combine: pair 1 -> LDS (f32 [64][68] + lsum[64], aliases Ks) ----
  float* Of = (float*)&Ks[0][0][0];
  float* Lf = Of + 64*68;
  const int rbase = qw*32;
  if (pair == 1) {
    #pragma unroll
    for (int mi = 0; mi < 2; ++mi)
      #pragma unroll
      for (int r = 0; r < 4; ++r) {
        int row = rbase + mi*16 + quad*4 + r;
        if (l16 == 0) Lf[row] = o5[mi][r];
        #pragma unroll
        for (int dt = 0; dt < 4; ++dt)
          Of[row*68 + dt*16 + l16] = o[mi][dt][r];
      }
  }
  __syncthreads();
  if (pair == 0) {
    #pragma unroll
    for (int mi = 0; mi < 2; ++mi)
      #pragma unroll
      for (int r = 0; r < 4; ++r) {
        int row = rbase + mi*16 + quad*4 + r;
        float inv = 1.f / (o5[mi][r] + Lf[row]);
        long trow = (long)(b*NS + q0 + row);
        #pragma unroll
        for (int dt = 0; dt < 4; ++dt)
          Ctx[trow*NE + h*64 + dt*16 + l16] =
            (bf16)((o[mi][dt][r] + Of[row*68 + dt*16 + l16]) * inv);
      }
  }
}

// ---------------- per-token: inter + build g/ones/zeros cols of Aext -----------
// 4 waves/block, one token per wave. Aext stride LDW; cols 1285..1343 zeroed.
// v2: xr read as bf16x2 (4B/lane coalescing), grow as bf16x8 store.
__global__ __launch_bounds__(256) void build_g(const bf16* __restrict__ HAB,
                                               const float* __restrict__ P,
                                               const float* __restrict__ hB_b2,
                                               bf16* __restrict__ Aext)
{
  long t = blockIdx.x*4 + (threadIdx.x >> 6);
  int lane = threadIdx.x & 63;
  const bf16* xr = Aext + t*LDW;             // cols 0..767 = xn2
  float acc[4] = {0.f, 0.f, 0.f, 0.f};
  #pragma unroll
  for (int k = 0; k < 6; ++k) {
    int idx = lane + k*64;                   // 0..383 (pairs)
    bf16x2 xv = *(const bf16x2*)(xr + idx*2);
    float x0 = (float)xv[0], x1 = (float)xv[1];
    #pragma unroll
    for (int r = 0; r < 4; ++r)
      acc[r] += x0 * hB_b2[r*768 + idx*2] + x1 * hB_b2[r*768 + idx*2 + 1];
  }
  const bf16* hB = HAB + t*256 + 128;
  const float* Pr = P + t*512;
  #pragma unroll
  for (int k = 0; k < 2; ++k) {
    int h = lane + k*64;
    float hv = (float)hB[h];
    #pragma unroll
    for (int r = 0; r < 4; ++r) acc[r] += hv * Pr[r*128 + h];
  }
  #pragma unroll
  for (int r = 0; r < 4; ++r)
    #pragma unroll
    for (int d = 1; d < 64; d <<= 1) acc[r] += __shfl_xor(acc[r], d, 64);

  bf16* grow = Aext + t*LDW + 768;
  const bf16* hA = HAB + t*256;
  bf16x8 gv;
  #pragma unroll
  for (int j = 0; j < 8; ++j) {
    int idx = lane*8 + j;                    // 0..511
    int h = idx >> 2, r = idx & 3;
    gv[j] = (bf16)((float)hA[h] * acc[r]);
  }
  *(bf16x8*)(grow + lane*8) = gv;
  if (lane < 4)       Aext[t*LDW + 1280 + lane] = (bf16)acc[lane];
  else if (lane == 4) Aext[t*LDW + 1284] = (bf16)1.0f;
  else                Aext[t*LDW + 1280 + lane] = (bf16)0.f;   // 1285..1343
}

// ---------------- host launcher ----------------
extern "C" void kernel_launch(void* const* d_in, const int* in_sizes, int n_in,
                              void* d_out, int out_size, void* d_ws, size_t ws_size,
                              hipStream_t stream)
{
  const float* src      = (const float*)d_in[0];
  const float* task     = (const float*)d_in[1];
  const float* norm1_w  = (const float*)d_in[2];
  const float* norm2_w  = (const float*)d_in[3];
  const float* in_proj  = (const float*)d_in[4];
  const float* out_proj = (const float*)d_in[5];
  const float* ffn1_w   = (const float*)d_in[6];
  const float* ffn1_b   = (const float*)d_in[7];
  const float* ffn2_w   = (const float*)d_in[8];
  const float* ffn2_b   = (const float*)d_in[9];
  const float* hA_w1    = (const float*)d_in[10];
  const float* hA_b1    = (const float*)d_in[11];
  const float* hA_w2    = (const float*)d_in[12];
  const float* hA_b2    = (const float*)d_in[13];
  const float* hB_w1    = (const float*)d_in[14];
  const float* hB_b1    = (const float*)d_in[15];
  const float* hB_w2    = (const float*)d_in[16];
  const float* hB_b2    = (const float*)d_in[17];
  float* out = (float*)d_out;

  char* ws = (char*)d_ws;
  size_t off = 0;
  auto alloc = [&](size_t bytes) { size_t o = off; off += (bytes + 255) & ~(size_t)255; return o; };
  bf16*  Wqkv   = (bf16*)(ws + alloc(2304*768*2));
  bf16*  Wo     = (bf16*)(ws + alloc(768*768*2));
  bf16*  W2     = (bf16*)(ws + alloc(768*3072*2));
  bf16*  W1ab   = (bf16*)(ws + alloc(256*128*2));
  float* b1ab   = (float*)(ws + alloc(256*4));
  bf16*  WBp    = (bf16*)(ws + alloc(512*768*2));
  bf16*  Wc     = (bf16*)(ws + alloc((size_t)3072*LDW*2));
  bf16*  taskbf = (bf16*)(ws + alloc((size_t)NTOK*128*2));
  bf16*  XC     = (bf16*)(ws + alloc((size_t)NTOK*768*2));    // Xn1, then Ctx
  char*  QKVH   = ws + alloc(25559040);                        // Qkv(18874368)+Vt(24*64*VTS*2=6684672) / Hbuf(25165824)
  bf16*  Qkv    = (bf16*)QKVH;
  bf16*  Vt     = (bf16*)(QKVH + 18874368);
  bf16*  Hbuf   = (bf16*)QKVH;
  float* Src2   = (float*)(ws + alloc((size_t)NTOK*768*4));
  bf16*  Aext   = (bf16*)(ws + alloc((size_t)NTOK*LDW*2));
  bf16*  HAB    = (bf16*)(ws + alloc((size_t)NTOK*256*2));
  float* P      = (float*)(ws + alloc((size_t)NTOK*512*4));

  // K0: weight prep / casts
  prep_kernel<<<dim3(1280), 256, 0, stream>>>(in_proj, out_proj, ffn1_w, ffn1_b, ffn2_w,
      hA_w1, hA_b1, hA_w2, hA_b2, hB_w1, hB_b1, hB_w2, task,
      Wqkv, Wo, W2, W1ab, b1ab, WBp, Wc, taskbf);
  // K1: x1 = rmsnorm(src, norm1_w) -> bf16
  rmsnorm_k<<<dim3(NTOK), 256, 0, stream>>>(src, norm1_w, XC, 768);
  // K2: qkv = x1 @ in_proj^T on the 4-phase structure; V -> Vt (stride VTS)
  gemm_ph_qkv<<<dim3(12,32), 256, 0, stream>>>(XC, Wqkv, Qkv, Vt);
  // K4: flash attention -> Ctx (reuses XC); 4 waves, KV-split, K+V in LDS
  flash_attn<<<dim3(32,24), 256, 0, stream>>>(Qkv, Vt, XC);
  // K5: src2 = src + ctx @ out_proj^T
  gemm64<float,false,false,true><<<dim3(12,64), 256, 0, stream>>>(XC, Wo, Src2, nullptr, src, 768, 768, 768, 768);
  // K6: xn2 = rmsnorm(src2, norm2_w) -> Aext cols 0..767 (stride LDW)
  rmsnorm_k<<<dim3(NTOK), 256, 0, stream>>>(Src2, norm2_w, Aext, LDW);
  // K7: HAB = relu(task @ W1ab^T + b1ab)
  gemm64<bf16,true,true,false><<<dim3(4,64), 256, 0, stream>>>(taskbf, W1ab, HAB, b1ab, nullptr, 128, 128, 128, 256);
  // K8: P = xn2 @ WBp^T
  gemm64<float,false,false,false><<<dim3(8,64), 256, 0, stream>>>(Aext, WBp, P, nullptr, nullptr, 768, LDW, 768, 512);
  // K9: inter + g -> Aext cols 768..1343
  build_g<<<dim3(NTOK/4), 256, 0, stream>>>(HAB, P, hB_b2, Aext);
  // K10: H = relu(Aext @ Wc^T) -- 128x192 4-phase counted-vmcnt, 512 blocks (R7 best)
  gemm_ph<<<dim3(16,32), 256, 0, stream>>>(Aext, Wc, Hbuf, 21, LDW, LDW, 3072);
  // K11: out = src2 + H @ ffn2_w^T + ffn2_b
  gemm64<float,false,true,true><<<dim3(12,64), 256, 0, stream>>>(Hbuf, W2, out, ffn2_b, Src2, 3072, 3072, 3072, 768);
}

// Round 11
// 204.899 us; speedup vs baseline: 1.0125x; 1.0019x over previous
//
#include <hip/hip_runtime.h>
#include <math.h>

// ---- problem constants ----
#define NB 2
#define NS 2048
#define NE 768
#define NF 3072
#define NHEAD 12
#define NTOK 4096   // B*S
#define LDW 1344    // padded inner dim for Aext/Wc (21*64)
#define VTS 2176    // Vt row stride (2048+128): 4352B = 17*256B -> rotates L2 channels

typedef __bf16 bf16;
typedef __bf16 bf16x2 __attribute__((ext_vector_type(2)));
typedef __bf16 bf16x4 __attribute__((ext_vector_type(4)));
typedef __bf16 bf16x8 __attribute__((ext_vector_type(8)));
typedef float  f32x4  __attribute__((ext_vector_type(4)));

__device__ __forceinline__ f32x4 mfma_bf16(bf16x8 a, bf16x8 b, f32x4 c) {
  return __builtin_amdgcn_mfma_f32_16x16x32_bf16(a, b, c, 0, 0, 0);
}

__device__ __forceinline__ float fast_exp2(float x) {
#if __has_builtin(__builtin_amdgcn_exp2f)
  return __builtin_amdgcn_exp2f(x);
#else
  return exp2f(x);
#endif
}

// async global->LDS, 16B per lane. LDS dest must be wave-uniform base + lane*16.
__device__ __forceinline__ void glds16(const void* g, void* l) {
  __builtin_amdgcn_global_load_lds((const __attribute__((address_space(1))) void*)g,
                                   (__attribute__((address_space(3))) void*)l,
                                   16, 0, 0);
}

// Counted-vmcnt pipeline barriers (tri-buf gemm64 structure).
__device__ __forceinline__ void pipe_barrier_keep4() {
  asm volatile("s_waitcnt vmcnt(4)" ::: "memory");
  __builtin_amdgcn_s_barrier();
  __builtin_amdgcn_sched_barrier(0);
}
__device__ __forceinline__ void pipe_barrier_drain() {
  asm volatile("s_waitcnt vmcnt(0)" ::: "memory");
  __builtin_amdgcn_s_barrier();
  __builtin_amdgcn_sched_barrier(0);
}

// XCD-band swizzle (gridDim.y % 8 == 0 at all call sites).
__device__ __forceinline__ void swz_xy(int& bx, int& by) {
  int gx = gridDim.x;
  int i = by*gx + bx;
  int xcd = i & 7, s = i >> 3;
  int bands = gridDim.y >> 3;
  by = xcd*bands + s / gx;
  bx = s % gx;
}

// ---------------- weight prep: fp32 -> bf16 (+ reshapes/concat) ----------------
__global__ void prep_kernel(const float* __restrict__ in_proj, const float* __restrict__ out_proj,
                            const float* __restrict__ ffn1_w, const float* __restrict__ ffn1_b,
                            const float* __restrict__ ffn2_w,
                            const float* __restrict__ hA_w1, const float* __restrict__ hA_b1,
                            const float* __restrict__ hA_w2, const float* __restrict__ hA_b2,
                            const float* __restrict__ hB_w1, const float* __restrict__ hB_b1,
                            const float* __restrict__ hB_w2,
                            const float* __restrict__ task,
                            bf16* __restrict__ Wqkv, bf16* __restrict__ Wo, bf16* __restrict__ W2,
                            bf16* __restrict__ W1ab, float* __restrict__ b1ab,
                            bf16* __restrict__ WBp, bf16* __restrict__ Wc,
                            bf16* __restrict__ task_bf)
{
  __shared__ float tb[64*130];
  int stride = gridDim.x * blockDim.x;
  int t0 = blockIdx.x * blockDim.x + threadIdx.x;
  // q rows (first 768) pre-scaled by (1/sqrt(HD)) * log2(e) so flash can use exp2
  const float QS = 0.125f * 1.44269504088896f;
  // vectorized fp32->bf16 casts (float4 in, bf16x4 out)
  for (int i = t0; i < (2304*768)/4; i += stride) {
    float4 v = ((const float4*)in_proj)[i];
    float sc = (i < (768*768)/4) ? QS : 1.0f;
    *(bf16x4*)(Wqkv + i*4) = (bf16x4){(bf16)(v.x*sc), (bf16)(v.y*sc), (bf16)(v.z*sc), (bf16)(v.w*sc)};
  }
  for (int i = t0; i < (768*768)/4; i += stride) {
    float4 v = ((const float4*)out_proj)[i];
    *(bf16x4*)(Wo + i*4) = (bf16x4){(bf16)v.x, (bf16)v.y, (bf16)v.z, (bf16)v.w};
  }
  for (int i = t0; i < (768*3072)/4; i += stride) {
    float4 v = ((const float4*)ffn2_w)[i];
    *(bf16x4*)(W2 + i*4) = (bf16x4){(bf16)v.x, (bf16)v.y, (bf16)v.z, (bf16)v.w};
  }
  for (int i = t0; i < (NTOK*128)/4; i += stride) {
    float4 v = ((const float4*)task)[i];
    *(bf16x4*)(task_bf + i*4) = (bf16x4){(bf16)v.x, (bf16)v.y, (bf16)v.z, (bf16)v.w};
  }
  for (int i = t0; i < 256*128;  i += stride)
    W1ab[i] = (bf16)(i < 128*128 ? hA_w1[i] : hB_w1[i - 128*128]);
  for (int i = t0; i < 256; i += stride) b1ab[i] = (i < 128) ? hA_b1[i] : hB_b1[i-128];

  // WBp[n=(r*128+h)][e] = hB_w2[r*768+e][h] via 64x128 LDS transpose
  for (int j0 = blockIdx.x*64; j0 < 3072; j0 += gridDim.x*64) {
    __syncthreads();
    for (int i = threadIdx.x; i < 64*128; i += 256) {
      int jr = i >> 7, hh = i & 127;
      tb[jr*130 + hh] = hB_w2[(long)(j0 + jr)*128 + hh];
    }
    __syncthreads();
    int r = j0 / 768, e0 = j0 % 768;
    for (int i = threadIdx.x; i < 128*64; i += 256) {
      int hh = i >> 6, jr = i & 63;
      WBp[(long)(r*128 + hh)*768 + e0 + jr] = (bf16)tb[jr*130 + hh];
    }
  }

  // Wc[f][0:768]=ffn1_w ; [768+h*4+r]=hA_w2[(f*4+r)][h] ; [1280+r]=hA_b2[f*4+r] ;
  // [1284]=ffn1_b[f] ; [1285:1344]=0.  (stride LDW=1344)
  for (int f = blockIdx.x; f < 3072; f += gridDim.x) {
    const float* hrow = hA_w2 + (long)f*512;
    bf16* wrow = Wc + (long)f*LDW;
    for (int c = threadIdx.x; c < 768; c += 256) wrow[c] = (bf16)ffn1_w[(long)f*768 + c];
    for (int i = threadIdx.x; i < 512; i += 256) {
      int r = i >> 7, h = i & 127;
      wrow[768 + h*4 + r] = (bf16)hrow[i];
    }
    if (threadIdx.x < 4)        wrow[1280 + threadIdx.x] = (bf16)hA_b2[f*4 + threadIdx.x];
    else if (threadIdx.x == 4)  wrow[1284] = (bf16)ffn1_b[f];
    else if (threadIdx.x < 64)  wrow[1280 + threadIdx.x] = (bf16)0.f;
  }
}

// ---------------- RMSNorm (fp32 in -> bf16 out, arbitrary out row stride) ------
__global__ __launch_bounds__(256) void rmsnorm_k(const float* __restrict__ x,
                                                 const float* __restrict__ w,
                                                 bf16* __restrict__ out, int ld_out)
{
  __shared__ float red[4];
  long t = blockIdx.x;
  const float* xr = x + t*NE;
  float ss = 0.f;
  #pragma unroll
  for (int i = 0; i < 3; i++) { float v = xr[threadIdx.x + i*256]; ss += v*v; }
  #pragma unroll
  for (int d = 1; d < 64; d <<= 1) ss += __shfl_xor(ss, d, 64);
  if ((threadIdx.x & 63) == 0) red[threadIdx.x >> 6] = ss;
  __syncthreads();
  float tot = red[0] + red[1] + red[2] + red[3];
  float scale = rsqrtf(tot * (1.f/768.f) + 1.1920928955078125e-07f);
  #pragma unroll
  for (int i = 0; i < 3; i++) {
    int idx = threadIdx.x + i*256;
    out[t*ld_out + idx] = (bf16)(xr[idx] * scale * w[idx]);
  }
}

// ------- 128x192 BK=64 4-wave 4-phase GEMM (counted-vmcnt schedule) ------------
// K10 (R7-verified best: 43.4us, MfmaUtil 30%). Grid (16,32) = 512 blocks =
// exactly 2/CU; LDS 80KB = exactly 160/2. 256 thr = 4 waves (2M x 2N); wave
// tile 64x96; acc 4x6 f32x4; 12 MFMA/phase.
// Sync ledger: A-khalf=2, B-khalf=3 glds16/thread -> 10 loads/tile, order
// A0(Ph1),B0(Ph2),A1(Ph3),B1(Ph4) into buf cur^1.
//  * A0,B0(t): vmcnt(5) at Ph4(t-1). A1,B1(t): vmcnt(5) at Ph2(t).
//  * Tail: vmcnt(0) at Ph2, no Ph4 wait.
__global__ __launch_bounds__(256, 2) void gemm_ph(const bf16* __restrict__ A,
                                                  const bf16* __restrict__ Bm,
                                                  bf16* __restrict__ C,
                                                  int nt, int lda, int ldb, int ldc)
{
  __shared__ bf16 As[2][2][128*32];   // [buf][khalf]
  __shared__ bf16 Bs[2][2][192*32];   // 80KB total with As
  const int tid = threadIdx.x;
  int bx = blockIdx.x, by = blockIdx.y;
  swz_xy(bx, by);                     // gridDim=(16,32), y%8==0
  const int m0 = by * 128, n0 = bx * 192;
  const int w = tid >> 6, lane = tid & 63;
  const int quad = lane >> 4, l16 = lane & 15;
  const int wm = w >> 1, wn = w & 1;

  f32x4 acc[4][6];
  #pragma unroll
  for (int i = 0; i < 4; i++)
    #pragma unroll
    for (int j = 0; j < 6; j++) acc[i][j] = (f32x4){0.f,0.f,0.f,0.f};

  const int iA0 = tid,      RA0 = iA0 >> 3, cA0 = (iA0 & 7) ^ (RA0 & 7);
  const int iA1 = tid + 256,RA1 = iA1 >> 3, cA1 = (iA1 & 7) ^ (RA1 & 7);
  const int iB2 = tid + 512,RB2 = iB2 >> 3, cB2 = (iB2 & 7) ^ (RB2 & 7);
  const int rA0 = 2*RA0 + (cA0 >> 2), hA0c = (cA0 & 3)*8;
  const int rA1 = 2*RA1 + (cA1 >> 2), hA1c = (cA1 & 3)*8;
  const int rB2 = 2*RB2 + (cB2 >> 2), hB2c = (cB2 & 3)*8;
  const bf16* paA0 = A  + (long)(m0 + rA0)*lda + hA0c;
  const bf16* paA1 = A  + (long)(m0 + rA1)*lda + hA1c;
  const bf16* pbB0 = Bm + (long)(n0 + rA0)*ldb + hA0c;
  const bf16* pbB1 = Bm + (long)(n0 + rA1)*ldb + hA1c;
  const bf16* pbB2 = Bm + (long)(n0 + rB2)*ldb + hB2c;

  auto stageA = [&](int buf, int kh, int kt) {
    const int s = kt + kh*32;
    glds16(paA0 + s, (void*)(&As[buf][kh][tid*8]));
    glds16(paA1 + s, (void*)(&As[buf][kh][(tid + 256)*8]));
  };
  auto stageB = [&](int buf, int kh, int kt) {
    const int s = kt + kh*32;
    glds16(pbB0 + s, (void*)(&Bs[buf][kh][tid*8]));
    glds16(pbB1 + s, (void*)(&Bs[buf][kh][(tid + 256)*8]));
    glds16(pbB2 + s, (void*)(&Bs[buf][kh][(tid + 512)*8]));
  };

  const int Rh = l16 >> 1;
  const int jfr = (((l16 & 1) << 2) | quad) ^ Rh;
  const int aBase = wm*32, bBase = wn*48;   // superrow bases (64 / 96 rows)

  auto barrier = [] { __builtin_amdgcn_s_barrier(); __builtin_amdgcn_sched_barrier(0); };

  // prologue: tile 0 (A0,B0,A1,B1 = 10 loads); drain A0,B0, keep A1,B1 in flight
  stageA(0, 0, 0); stageB(0, 0, 0); stageA(0, 1, 0); stageB(0, 1, 0);
  asm volatile("s_waitcnt vmcnt(5)" ::: "memory");
  barrier();

  for (int t = 0; t < nt; ++t) {
    const int cur = t & 1, nb = cur ^ 1;
    const bool more = (t + 1 < nt);
    const int kt1 = (t + 1) << 6;
    bf16x8 af[2], bfr[6];

    // ---- Ph1: kb=0, mh=0 (mi 0..1) ----
    #pragma unroll
    for (int j = 0; j < 2; ++j)
      af[j] = *(const bf16x8*)(&As[cur][0][(aBase + j*8 + Rh)*64 + jfr*8]);
    #pragma unroll
    for (int ni = 0; ni < 6; ++ni)
      bfr[ni] = *(const bf16x8*)(&Bs[cur][0][(bBase + ni*8 + Rh)*64 + jfr*8]);
    if (more) stageA(nb, 0, kt1);
    barrier();
    __builtin_amdgcn_s_setprio(1);
    #pragma unroll
    for (int j = 0; j < 2; ++j)
      #pragma unroll
      for (int ni = 0; ni < 6; ++ni)
        acc[j][ni] = mfma_bf16(af[j], bfr[ni], acc[j][ni]);
    __builtin_amdgcn_s_setprio(0);
    barrier();

    // ---- Ph2: kb=0, mh=1 (mi 2..3) ----
    #pragma unroll
    for (int j = 0; j < 2; ++j)
      af[j] = *(const bf16x8*)(&As[cur][0][(aBase + 16 + j*8 + Rh)*64 + jfr*8]);
    if (more) stageB(nb, 0, kt1);
    barrier();
    __builtin_amdgcn_s_setprio(1);
    #pragma unroll
    for (int j = 0; j < 2; ++j)
      #pragma unroll
      for (int ni = 0; ni < 6; ++ni)
        acc[2 + j][ni] = mfma_bf16(af[j], bfr[ni], acc[2 + j][ni]);
    __builtin_amdgcn_s_setprio(0);
    if (more) asm volatile("s_waitcnt vmcnt(5)" ::: "memory");
    else      asm volatile("s_waitcnt vmcnt(0)" ::: "memory");
    barrier();   // A1,B1(t) now visible to all waves

    // ---- Ph3: kb=1, mh=0 ----
    #pragma unroll
    for (int j = 0; j < 2; ++j)
      af[j] = *(const bf16x8*)(&As[cur][1][(aBase + j*8 + Rh)*64 + jfr*8]);
    #pragma unroll
    for (int ni = 0; ni < 6; ++ni)
      bfr[ni] = *(const bf16x8*)(&Bs[cur][1][(bBase + ni*8 + Rh)*64 + jfr*8]);
    if (more) stageA(nb, 1, kt1);
    barrier();
    __builtin_amdgcn_s_setprio(1);
    #pragma unroll
    for (int j = 0; j < 2; ++j)
      #pragma unroll
      for (int ni = 0; ni < 6; ++ni)
        acc[j][ni] = mfma_bf16(af[j], bfr[ni], acc[j][ni]);
    __builtin_amdgcn_s_setprio(0);
    barrier();

    // ---- Ph4: kb=1, mh=1 ----
    #pragma unroll
    for (int j = 0; j < 2; ++j)
      af[j] = *(const bf16x8*)(&As[cur][1][(aBase + 16 + j*8 + Rh)*64 + jfr*8]);
    if (more) stageB(nb, 1, kt1);
    barrier();
    __builtin_amdgcn_s_setprio(1);
    #pragma unroll
    for (int j = 0; j < 2; ++j)
      #pragma unroll
      for (int ni = 0; ni < 6; ++ni)
        acc[2 + j][ni] = mfma_bf16(af[j], bfr[ni], acc[2 + j][ni]);
    __builtin_amdgcn_s_setprio(0);
    if (more) asm volatile("s_waitcnt vmcnt(5)" ::: "memory");
    barrier();   // A0,B0(t+1) now visible to all waves
  }

  // epilogue: relu, bf16 out
  #pragma unroll
  for (int mi = 0; mi < 4; ++mi)
    #pragma unroll
    for (int ni = 0; ni < 6; ++ni) {
      int col = n0 + wn*96 + ni*16 + l16;
      #pragma unroll
      for (int r = 0; r < 4; ++r) {
        long row = m0 + wm*64 + mi*16 + quad*4 + r;
        float v = acc[mi][ni][r];
        C[row*ldc + col] = (bf16)(v > 0.f ? v : 0.f);
      }
    }
}

// ---- QKV on the gemm_ph structure (exact clone; epilogue swapped) -------------
// M=4096, N=2304 (12 col-tiles of 192), K=768 (nt=12). Grid (12,32) = 384
// blocks = 1.5/CU. Epilogue: col<1536 -> Qkv[t][2304] (q pre-scaled in Wqkv);
// col>=1536 -> Vt[bh][d][s] scatter (stride VTS).
__global__ __launch_bounds__(256, 2) void gemm_ph_qkv(const bf16* __restrict__ A,
                                                      const bf16* __restrict__ Bm,
                                                      bf16* __restrict__ Qkv,
                                                      bf16* __restrict__ Vt)
{
  __shared__ bf16 As[2][2][128*32];
  __shared__ bf16 Bs[2][2][192*32];
  const int tid = threadIdx.x;
  int bx = blockIdx.x, by = blockIdx.y;
  swz_xy(bx, by);                     // gridDim=(12,32), y%8==0
  const int m0 = by * 128, n0 = bx * 192;
  const int w = tid >> 6, lane = tid & 63;
  const int quad = lane >> 4, l16 = lane & 15;
  const int wm = w >> 1, wn = w & 1;
  const int lda = 768, ldb = 768, nt = 12;

  f32x4 acc[4][6];
  #pragma unroll
  for (int i = 0; i < 4; i++)
    #pragma unroll
    for (int j = 0; j < 6; j++) acc[i][j] = (f32x4){0.f,0.f,0.f,0.f};

  const int iA0 = tid,      RA0 = iA0 >> 3, cA0 = (iA0 & 7) ^ (RA0 & 7);
  const int iA1 = tid + 256,RA1 = iA1 >> 3, cA1 = (iA1 & 7) ^ (RA1 & 7);
  const int iB2 = tid + 512,RB2 = iB2 >> 3, cB2 = (iB2 & 7) ^ (RB2 & 7);
  const int rA0 = 2*RA0 + (cA0 >> 2), hA0c = (cA0 & 3)*8;
  const int rA1 = 2*RA1 + (cA1 >> 2), hA1c = (cA1 & 3)*8;
  const int rB2 = 2*RB2 + (cB2 >> 2), hB2c = (cB2 & 3)*8;
  const bf16* paA0 = A  + (long)(m0 + rA0)*lda + hA0c;
  const bf16* paA1 = A  + (long)(m0 + rA1)*lda + hA1c;
  const bf16* pbB0 = Bm + (long)(n0 + rA0)*ldb + hA0c;
  const bf16* pbB1 = Bm + (long)(n0 + rA1)*ldb + hA1c;
  const bf16* pbB2 = Bm + (long)(n0 + rB2)*ldb + hB2c;

  auto stageA = [&](int buf, int kh, int kt) {
    const int s = kt + kh*32;
    glds16(paA0 + s, (void*)(&As[buf][kh][tid*8]));
    glds16(paA1 + s, (void*)(&As[buf][kh][(tid + 256)*8]));
  };
  auto stageB = [&](int buf, int kh, int kt) {
    const int s = kt + kh*32;
    glds16(pbB0 + s, (void*)(&Bs[buf][kh][tid*8]));
    glds16(pbB1 + s, (void*)(&Bs[buf][kh][(tid + 256)*8]));
    glds16(pbB2 + s, (void*)(&Bs[buf][kh][(tid + 512)*8]));
  };

  const int Rh = l16 >> 1;
  const int jfr = (((l16 & 1) << 2) | quad) ^ Rh;
  const int aBase = wm*32, bBase = wn*48;

  auto barrier = [] { __builtin_amdgcn_s_barrier(); __builtin_amdgcn_sched_barrier(0); };

  stageA(0, 0, 0); stageB(0, 0, 0); stageA(0, 1, 0); stageB(0, 1, 0);
  asm volatile("s_waitcnt vmcnt(5)" ::: "memory");
  barrier();

  for (int t = 0; t < nt; ++t) {
    const int cur = t & 1, nb = cur ^ 1;
    const bool more = (t + 1 < nt);
    const int kt1 = (t + 1) << 6;
    bf16x8 af[2], bfr[6];

    // ---- Ph1 ----
    #pragma unroll
    for (int j = 0; j < 2; ++j)
      af[j] = *(const bf16x8*)(&As[cur][0][(aBase + j*8 + Rh)*64 + jfr*8]);
    #pragma unroll
    for (int ni = 0; ni < 6; ++ni)
      bfr[ni] = *(const bf16x8*)(&Bs[cur][0][(bBase + ni*8 + Rh)*64 + jfr*8]);
    if (more) stageA(nb, 0, kt1);
    barrier();
    __builtin_amdgcn_s_setprio(1);
    #pragma unroll
    for (int j = 0; j < 2; ++j)
      #pragma unroll
      for (int ni = 0; ni < 6; ++ni)
        acc[j][ni] = mfma_bf16(af[j], bfr[ni], acc[j][ni]);
    __builtin_amdgcn_s_setprio(0);
    barrier();

    // ---- Ph2 ----
    #pragma unroll
    for (int j = 0; j < 2; ++j)
      af[j] = *(const bf16x8*)(&As[cur][0][(aBase + 16 + j*8 + Rh)*64 + jfr*8]);
    if (more) stageB(nb, 0, kt1);
    barrier();
    __builtin_amdgcn_s_setprio(1);
    #pragma unroll
    for (int j = 0; j < 2; ++j)
      #pragma unroll
      for (int ni = 0; ni < 6; ++ni)
        acc[2 + j][ni] = mfma_bf16(af[j], bfr[ni], acc[2 + j][ni]);
    __builtin_amdgcn_s_setprio(0);
    if (more) asm volatile("s_waitcnt vmcnt(5)" ::: "memory");
    else      asm volatile("s_waitcnt vmcnt(0)" ::: "memory");
    barrier();

    // ---- Ph3 ----
    #pragma unroll
    for (int j = 0; j < 2; ++j)
      af[j] = *(const bf16x8*)(&As[cur][1][(aBase + j*8 + Rh)*64 + jfr*8]);
    #pragma unroll
    for (int ni = 0; ni < 6; ++ni)
      bfr[ni] = *(const bf16x8*)(&Bs[cur][1][(bBase + ni*8 + Rh)*64 + jfr*8]);
    if (more) stageA(nb, 1, kt1);
    barrier();
    __builtin_amdgcn_s_setprio(1);
    #pragma unroll
    for (int j = 0; j < 2; ++j)
      #pragma unroll
      for (int ni = 0; ni < 6; ++ni)
        acc[j][ni] = mfma_bf16(af[j], bfr[ni], acc[j][ni]);
    __builtin_amdgcn_s_setprio(0);
    barrier();

    // ---- Ph4 ----
    #pragma unroll
    for (int j = 0; j < 2; ++j)
      af[j] = *(const bf16x8*)(&As[cur][1][(aBase + 16 + j*8 + Rh)*64 + jfr*8]);
    if (more) stageB(nb, 1, kt1);
    barrier();
    __builtin_amdgcn_s_setprio(1);
    #pragma unroll
    for (int j = 0; j < 2; ++j)
      #pragma unroll
      for (int ni = 0; ni < 6; ++ni)
        acc[2 + j][ni] = mfma_bf16(af[j], bfr[ni], acc[2 + j][ni]);
    __builtin_amdgcn_s_setprio(0);
    if (more) asm volatile("s_waitcnt vmcnt(5)" ::: "memory");
    barrier();
  }

  // epilogue: QKV split store (bf16, no relu)
  #pragma unroll
  for (int mi = 0; mi < 4; ++mi)
    #pragma unroll
    for (int ni = 0; ni < 6; ++ni) {
      int col = n0 + wn*96 + ni*16 + l16;
      #pragma unroll
      for (int r = 0; r < 4; ++r) {
        long row = m0 + wm*64 + mi*16 + quad*4 + r;
        bf16 v = (bf16)acc[mi][ni][r];
        if (col < 1536) {
          Qkv[row*2304 + col] = v;
        } else {
          int vc = col - 1536;
          int hh = vc >> 6, d = vc & 63;
          long bb = row >> 11;
          long srow = row & (NS-1);
          Vt[((bb*NHEAD + hh)*64 + d)*VTS + srow] = v;
        }
      }
    }
}

// ---------------- 64x64-tile GEMM, BK=64, XOR-swizzled LDS --------------------
// tri-buf counted-vmcnt pipeline.
template<typename OutT, bool RELU, bool BIAS, bool RES>
__global__ __launch_bounds__(256) void gemm64(const bf16* __restrict__ A,
                                              const bf16* __restrict__ Bm,
                                              OutT* __restrict__ C,
                                              const float* __restrict__ bias,
                                              const float* __restrict__ res,
                                              int K, int lda, int ldb, int ldc)
{
  __shared__ bf16 As[3][64*64];
  __shared__ bf16 Bs[3][64*64];
  const int tid = threadIdx.x;
  int bx = blockIdx.x, by = blockIdx.y;
  swz_xy(bx, by);
  const int m0 = by * 64, n0 = bx * 64;
  const int w = tid >> 6, lane = tid & 63;
  const int quad = lane >> 4, l16 = lane & 15;
  const int wy = w >> 1, wx = w & 1;
  const int sw = l16 & 7;

  f32x4 acc[2][2];
  #pragma unroll
  for (int i = 0; i < 2; i++)
    #pragma unroll
    for (int j = 0; j < 2; j++) acc[i][j] = (f32x4){0.f,0.f,0.f,0.f};

  const int c0 = tid, c1 = tid + 256;
  const int r0 = c0 >> 3, g0 = ((c0 & 7) ^ (r0 & 7)) * 8;
  const int r1 = c1 >> 3, g1 = ((c1 & 7) ^ (r1 & 7)) * 8;
  const bf16* pA0 = A  + (long)(m0 + r0)*lda + g0;
  const bf16* pA1 = A  + (long)(m0 + r1)*lda + g1;
  const bf16* pB0 = Bm + (long)(n0 + r0)*ldb + g0;
  const bf16* pB1 = Bm + (long)(n0 + r1)*ldb + g1;
  auto stage = [&](int buf) {
    glds16(pA0, (void*)(&As[buf][c0*8]));
    glds16(pA1, (void*)(&As[buf][c1*8]));
    glds16(pB0, (void*)(&Bs[buf][c0*8]));
    glds16(pB1, (void*)(&Bs[buf][c1*8]));
    pA0 += 64; pA1 += 64; pB0 += 64; pB1 += 64;
  };

  const int nsteps = K >> 6;
  stage(0);
  if (nsteps > 1) stage(1);
  pipe_barrier_keep4();

  int cur = 0, nx2 = 2;
  for (int s = 0; s < nsteps; ++s) {
    const bool more = (s + 2 < nsteps);
    if (more) stage(nx2);

    bf16x8 af[2][2], bfr[2][2];
    #pragma unroll
    for (int mi = 0; mi < 2; ++mi)
      #pragma unroll
      for (int kb = 0; kb < 2; ++kb)
        af[mi][kb] = *(const bf16x8*)(&As[cur][(wy*32 + mi*16 + l16)*64 + (((kb*4 + quad) ^ sw))*8]);
    #pragma unroll
    for (int ni = 0; ni < 2; ++ni)
      #pragma unroll
      for (int kb = 0; kb < 2; ++kb)
        bfr[ni][kb] = *(const bf16x8*)(&Bs[cur][(wx*32 + ni*16 + l16)*64 + (((kb*4 + quad) ^ sw))*8]);
    #pragma unroll
    for (int kb = 0; kb < 2; ++kb)
      #pragma unroll
      for (int mi = 0; mi < 2; ++mi)
        #pragma unroll
        for (int ni = 0; ni < 2; ++ni)
          acc[mi][ni] = mfma_bf16(af[mi][kb], bfr[ni][kb], acc[mi][ni]);

    if (more) pipe_barrier_keep4();
    else      pipe_barrier_drain();
    cur = (cur == 2) ? 0 : cur + 1;
    nx2 = (nx2 == 2) ? 0 : nx2 + 1;
  }

  #pragma unroll
  for (int mi = 0; mi < 2; ++mi)
    #pragma unroll
    for (int ni = 0; ni < 2; ++ni) {
      int col = n0 + wx*32 + ni*16 + l16;
      #pragma unroll
      for (int r = 0; r < 4; ++r) {
        long row = m0 + wy*32 + mi*16 + quad*4 + r;
        float v = acc[mi][ni][r];
        if (BIAS) v += bias[col];
        if (RES)  v += res[row*ldc + col];
        if (RELU) v = v > 0.f ? v : 0.f;
        C[row*ldc + col] = (OutT)v;
      }
    }
}

// ---------------- flash attention v8: single-buffered V -> 3 blocks/CU --------
// Pairs (pair=w>>1) each cover kv [pair*1024,(pair+1)*1024); wave qw owns
// q-rows [qw*32,qw*32+32). K double-buffered, V SINGLE-buffered: V(t) staged
// at top of iter t, first read only after QK^T+exp2 (~400cy cover). LDS
// 48KB (Ks 32K + Vs 16K) -> 3 blocks/CU (grid 768 = exactly 3/CU, was 2).
// Counted-vmcnt ledger (per wave, uniform: 4 V then 4 K loads/iter):
//  * after exp2: vmcnt(4) drains V(t) (oldest 4), K(t+1) stays in flight
//    across the barrier. Tail iter (no K): vmcnt(0).
//  * after PV: vmcnt(0) drains K(t+1) (cover = PV's 20 MFMA + prior wait);
//    end barrier protects Vs overwrite + Ks[nb] reads next iter.
__global__ __launch_bounds__(256, 3) void flash_attn(const bf16* __restrict__ Qkv,
                                                     const bf16* __restrict__ Vt,
                                                     bf16* __restrict__ Ctx)
{
  __shared__ bf16 Ks[2][2][64*64];   // [pair][buf]  32KB
  __shared__ bf16 Vs[2][64*64];      // [pair]       16KB

  const int tid = threadIdx.x;
  const int w = tid >> 6, lane = tid & 63;
  const int quad = lane >> 4, l16 = lane & 15;
  const int pair = w >> 1, qw = w & 1;
  int bx = blockIdx.x, by = blockIdx.y;
  swz_xy(bx, by);                    // bh-band per XCD -> K/V L2-resident
  const int bh = by;
  const int b = bh / NHEAD, h = bh % NHEAD;
  const int q0 = bx * 64;

  bf16x8 qf[2][2];   // [q-group][kb]
  #pragma unroll
  for (int mi = 0; mi < 2; ++mi) {
    const long tq = (long)(b*NS + q0 + qw*32 + mi*16 + l16);
    qf[mi][0] = *(const bf16x8*)(Qkv + tq*2304 + h*64 + quad*8);
    qf[mi][1] = *(const bf16x8*)(Qkv + tq*2304 + h*64 + 32 + quad*8);
  }

  bf16x8 ones;
  #pragma unroll
  for (int j = 0; j < 8; ++j) ones[j] = (bf16)1.0f;

  f32x4 o[2][4];
  f32x4 o5[2];
  #pragma unroll
  for (int mi = 0; mi < 2; ++mi) {
    o5[mi] = (f32x4){0.f,0.f,0.f,0.f};
    #pragma unroll
    for (int i = 0; i < 4; i++) o[mi][i] = (f32x4){0.f,0.f,0.f,0.f};
  }

  // staging: per pair, 128 threads x 4 chunks each for K and V (512 = 64x64)
  const int ptid = tid & 127;
  const bf16* kp[4];
  const bf16* vp[4];
  int cc[4];
  #pragma unroll
  for (int i = 0; i < 4; ++i) {
    int c = ptid + i*128;
    cc[i] = c;
    int r = c >> 3, g = ((c & 7) ^ (r & 7)) * 8;
    kp[i] = Qkv + (long)(b*NS + pair*1024 + r)*2304 + 768 + h*64 + g;
    vp[i] = Vt + ((long)bh*64 + r)*VTS + pair*1024 + g;
  }
  auto stageK = [&](int buf) {
    #pragma unroll
    for (int i = 0; i < 4; ++i) {
      glds16(kp[i], (void*)(&Ks[pair][buf][cc[i]*8]));
      kp[i] += (long)64*2304;
    }
  };
  auto stageV = [&]() {
    #pragma unroll
    for (int i = 0; i < 4; ++i) {
      glds16(vp[i], (void*)(&Vs[pair][cc[i]*8]));
      vp[i] += 64;
    }
  };

  // prologue: K(0)
  stageK(0);
  asm volatile("s_waitcnt vmcnt(0)" ::: "memory");
  __builtin_amdgcn_s_barrier();
  __builtin_amdgcn_sched_barrier(0);

  for (int t = 0; t < 16; ++t) {
    const int cur = t & 1;
    const bool more = (t + 1 < 16);
    stageV();                       // V(t): 4 loads (oldest)
    if (more) stageK(cur ^ 1);      // K(t+1): 4 loads

    // ---- QK^T from Ks[pair][cur] + exp2 ----
    bf16x8 kfr[4][2];
    #pragma unroll
    for (int nt = 0; nt < 4; ++nt)
      #pragma unroll
      for (int kb = 0; kb < 2; ++kb)
        kfr[nt][kb] = *(const bf16x8*)(&Ks[pair][cur][(nt*16 + l16)*64 + (((kb*4 + quad) ^ (l16 & 7)))*8]);

    bf16x8 pf[2][2];   // [q-group][ntp]
    #pragma unroll
    for (int mi = 0; mi < 2; ++mi) {
      f32x4 s[4];
      #pragma unroll
      for (int nt = 0; nt < 4; ++nt) {
        s[nt] = (f32x4){0.f,0.f,0.f,0.f};
        #pragma unroll
        for (int kb = 0; kb < 2; ++kb)
          s[nt] = mfma_bf16(kfr[nt][kb], qf[mi][kb], s[nt]);   // A=K, B=Q -> S^T
      }
      #pragma unroll
      for (int nt = 0; nt < 4; ++nt)
        #pragma unroll
        for (int r = 0; r < 4; ++r)
          pf[mi][nt >> 1][(nt & 1)*4 + r] = (bf16)fast_exp2(s[nt][r]);
    }

    // V(t) visible: drain oldest 4 (V), keep K(t+1) in flight
    if (more) asm volatile("s_waitcnt vmcnt(4)" ::: "memory");
    else      asm volatile("s_waitcnt vmcnt(0)" ::: "memory");
    __builtin_amdgcn_s_barrier();
    __builtin_amdgcn_sched_barrier(0);

    // ---- PV from Vs[pair] ----
    #pragma unroll
    for (int ntp = 0; ntp < 2; ++ntp) {
      bf16x8 vf[4];
      #pragma unroll
      for (int dt = 0; dt < 4; ++dt) {
        int row = dt*16 + l16;                       // d
        int cA = ntp*4 + (quad >> 1);
        int base = row*64 + (quad & 1)*4;
        bf16x4 va = *(const bf16x4*)(&Vs[pair][base + ((cA       ^ (row & 7)) << 3)]);
        bf16x4 vb = *(const bf16x4*)(&Vs[pair][base + (((cA + 2) ^ (row & 7)) << 3)]);
        vf[dt] = (bf16x8){va[0],va[1],va[2],va[3], vb[0],vb[1],vb[2],vb[3]};
      }
      #pragma unroll
      for (int mi = 0; mi < 2; ++mi) {
        #pragma unroll
        for (int dt = 0; dt < 4; ++dt)
          o[mi][dt] = mfma_bf16(pf[mi][ntp], vf[dt], o[mi][dt]);
        o5[mi] = mfma_bf16(pf[mi][ntp], ones, o5[mi]);   // lsum in C-layout
      }
    }

    // drain K(t+1) (covered by PV); barrier protects Vs overwrite + Ks[nb] reads
    asm volatile("s_waitcnt vmcnt(0)" ::: "memory");
    __builtin_amdgcn_s_barrier();
    __builtin_amdgcn_sched_barrier(0);
  }

  // ---- combine: pair 1 -> LDS (f32 [64][68] + lsum[64], aliases Ks) ----
  float* Of = (float*)&Ks[0][0][0];
  float* Lf = Of + 64*68;
  const int rbase = qw*32;
  if (pair == 1) {
    #pragma unroll
    for (int mi = 0; mi < 2; ++mi)
      #pragma unroll
      for (int r = 0; r < 4; ++r) {
        int row = rbase + mi*16 + quad*4 + r;
        if (l16 == 0) Lf[row] = o5[mi][r];
        #pragma unroll
        for (int dt = 0; dt < 4; ++dt)
          Of[row*68 + dt*16 + l16] = o[mi][dt][r];
      }
  }
  __syncthreads();
  if (pair == 0) {
    #pragma unroll
    for (int mi = 0; mi < 2; ++mi)
      #pragma unroll
      for (int r = 0; r < 4; ++r) {
        int row = rbase + mi*16 + quad*4 + r;
        float inv = 1.f / (o5[mi][r] + Lf[row]);
        long trow = (long)(b*NS + q0 + row);
        #pragma unroll
        for (int dt = 0; dt < 4; ++dt)
          Ctx[trow*NE + h*64 + dt*16 + l16] =
            (bf16)((o[mi][dt][r] + Of[row*68 + dt*16 + l16]) * inv);
      }
  }
}

// ---------------- per-token: inter + build g/ones/zeros cols of Aext -----------
// 4 waves/block, one token per wave. Aext stride LDW; cols 1285..1343 zeroed.
// v2: xr read as bf16x2 (4B/lane coalescing), grow as bf16x8 store.
__global__ __launch_bounds__(256) void build_g(const bf16* __restrict__ HAB,
                                               const float* __restrict__ P,
                                               const float* __restrict__ hB_b2,
                                               bf16* __restrict__ Aext)
{
  long t = blockIdx.x*4 + (threadIdx.x >> 6);
  int lane = threadIdx.x & 63;
  const bf16* xr = Aext + t*LDW;             // cols 0..767 = xn2
  float acc[4] = {0.f, 0.f, 0.f, 0.f};
  #pragma unroll
  for (int k = 0; k < 6; ++k) {
    int idx = lane + k*64;                   // 0..383 (pairs)
    bf16x2 xv = *(const bf16x2*)(xr + idx*2);
    float x0 = (float)xv[0], x1 = (float)xv[1];
    #pragma unroll
    for (int r = 0; r < 4; ++r)
      acc[r] += x0 * hB_b2[r*768 + idx*2] + x1 * hB_b2[r*768 + idx*2 + 1];
  }
  const bf16* hB = HAB + t*256 + 128;
  const float* Pr = P + t*512;
  #pragma unroll
  for (int k = 0; k < 2; ++k) {
    int h = lane + k*64;
    float hv = (float)hB[h];
    #pragma unroll
    for (int r = 0; r < 4; ++r) acc[r] += hv * Pr[r*128 + h];
  }
  #pragma unroll
  for (int r = 0; r < 4; ++r)
    #pragma unroll
    for (int d = 1; d < 64; d <<= 1) acc[r] += __shfl_xor(acc[r], d, 64);

  bf16* grow = Aext + t*LDW + 768;
  const bf16* hA = HAB + t*256;
  bf16x8 gv;
  #pragma unroll
  for (int j = 0; j < 8; ++j) {
    int idx = lane*8 + j;                    // 0..511
    int h = idx >> 2, r = idx & 3;
    gv[j] = (bf16)((float)hA[h] * acc[r]);
  }
  *(bf16x8*)(grow + lane*8) = gv;
  if (lane < 4)       Aext[t*LDW + 1280 + lane] = (bf16)acc[lane];
  else if (lane == 4) Aext[t*LDW + 1284] = (bf16)1.0f;
  else                Aext[t*LDW + 1280 + lane] = (bf16)0.f;   // 1285..1343
}

// ---------------- host launcher ----------------
extern "C" void kernel_launch(void* const* d_in, const int* in_sizes, int n_in,
                              void* d_out, int out_size, void* d_ws, size_t ws_size,
                              hipStream_t stream)
{
  const float* src      = (const float*)d_in[0];
  const float* task     = (const float*)d_in[1];
  const float* norm1_w  = (const float*)d_in[2];
  const float* norm2_w  = (const float*)d_in[3];
  const float* in_proj  = (const float*)d_in[4];
  const float* out_proj = (const float*)d_in[5];
  const float* ffn1_w   = (const float*)d_in[6];
  const float* ffn1_b   = (const float*)d_in[7];
  const float* ffn2_w   = (const float*)d_in[8];
  const float* ffn2_b   = (const float*)d_in[9];
  const float* hA_w1    = (const float*)d_in[10];
  const float* hA_b1    = (const float*)d_in[11];
  const float* hA_w2    = (const float*)d_in[12];
  const float* hA_b2    = (const float*)d_in[13];
  const float* hB_w1    = (const float*)d_in[14];
  const float* hB_b1    = (const float*)d_in[15];
  const float* hB_w2    = (const float*)d_in[16];
  const float* hB_b2    = (const float*)d_in[17];
  float* out = (float*)d_out;

  char* ws = (char*)d_ws;
  size_t off = 0;
  auto alloc = [&](size_t bytes) { size_t o = off; off += (bytes + 255) & ~(size_t)255; return o; };
  bf16*  Wqkv   = (bf16*)(ws + alloc(2304*768*2));
  bf16*  Wo     = (bf16*)(ws + alloc(768*768*2));
  bf16*  W2     = (bf16*)(ws + alloc(768*3072*2));
  bf16*  W1ab   = (bf16*)(ws + alloc(256*128*2));
  float* b1ab   = (float*)(ws + alloc(256*4));
  bf16*  WBp    = (bf16*)(ws + alloc(512*768*2));
  bf16*  Wc     = (bf16*)(ws + alloc((size_t)3072*LDW*2));
  bf16*  taskbf = (bf16*)(ws + alloc((size_t)NTOK*128*2));
  bf16*  XC     = (bf16*)(ws + alloc((size_t)NTOK*768*2));    // Xn1, then Ctx
  char*  QKVH   = ws + alloc(25559040);                        // Qkv(18874368)+Vt(24*64*VTS*2=6684672) / Hbuf(25165824)
  bf16*  Qkv    = (bf16*)QKVH;
  bf16*  Vt     = (bf16*)(QKVH + 18874368);
  bf16*  Hbuf   = (bf16*)QKVH;
  float* Src2   = (float*)(ws + alloc((size_t)NTOK*768*4));
  bf16*  Aext   = (bf16*)(ws + alloc((size_t)NTOK*LDW*2));
  bf16*  HAB    = (bf16*)(ws + alloc((size_t)NTOK*256*2));
  float* P      = (float*)(ws + alloc((size_t)NTOK*512*4));

  // K0: weight prep / casts
  prep_kernel<<<dim3(1280), 256, 0, stream>>>(in_proj, out_proj, ffn1_w, ffn1_b, ffn2_w,
      hA_w1, hA_b1, hA_w2, hA_b2, hB_w1, hB_b1, hB_w2, task,
      Wqkv, Wo, W2, W1ab, b1ab, WBp, Wc, taskbf);
  // K1: x1 = rmsnorm(src, norm1_w) -> bf16
  rmsnorm_k<<<dim3(NTOK), 256, 0, stream>>>(src, norm1_w, XC, 768);
  // K2: qkv = x1 @ in_proj^T on the 4-phase structure; V -> Vt (stride VTS)
  gemm_ph_qkv<<<dim3(12,32), 256, 0, stream>>>(XC, Wqkv, Qkv, Vt);
  // K4: flash attention -> Ctx (reuses XC); single-buf V, 3 blocks/CU
  flash_attn<<<dim3(32,24), 256, 0, stream>>>(Qkv, Vt, XC);
  // K5: src2 = src + ctx @ out_proj^T
  gemm64<float,false,false,true><<<dim3(12,64), 256, 0, stream>>>(XC, Wo, Src2, nullptr, src, 768, 768, 768, 768);
  // K6: xn2 = rmsnorm(src2, norm2_w) -> Aext cols 0..767 (stride LDW)
  rmsnorm_k<<<dim3(NTOK), 256, 0, stream>>>(Src2, norm2_w, Aext, LDW);
  // K7: HAB = relu(task @ W1ab^T + b1ab)
  gemm64<bf16,true,true,false><<<dim3(4,64), 256, 0, stream>>>(taskbf, W1ab, HAB, b1ab, nullptr, 128, 128, 128, 256);
  // K8: P = xn2 @ WBp^T
  gemm64<float,false,false,false><<<dim3(8,64), 256, 0, stream>>>(Aext, WBp, P, nullptr, nullptr, 768, LDW, 768, 512);
  // K9: inter + g -> Aext cols 768..1343
  build_g<<<dim3(NTOK/4), 256, 0, stream>>>(HAB, P, hB_b2, Aext);
  // K10: H = relu(Aext @ Wc^T) -- 128x192 4-phase counted-vmcnt, 512 blocks (R7 best)
  gemm_ph<<<dim3(16,32), 256, 0, stream>>>(Aext, Wc, Hbuf, 21, LDW, LDW, 3072);
  // K11: out = src2 + H @ ffn2_w^T + ffn2_b
  gemm64<float,false,true,true><<<dim3(12,64), 256, 0, stream>>>(Hbuf, W2, out, ffn2_b, Src2, 3072, 3072, 3072, 768);
}